// Round 1
// baseline (556.096 us; speedup 1.0000x reference)
//
#include <hip/hip_runtime.h>
#include <math.h>

#define NHEADS 4
#define DKK 16
#define CC 64
#define BB 2
#define NN 4096
#define EPSF 1e-8f

// ---------------------------------------------------------------------------
// Stage 1: projections q,k,v = x @ (w/8) per head, then L2-normalize q,k rows.
// One thread per (b,h,n). x reads coalesced across n; weights staged in LDS.
// ---------------------------------------------------------------------------
__global__ __launch_bounds__(256) void proj_kernel(
    const float* __restrict__ x, const float* __restrict__ wq,
    const float* __restrict__ wk, const float* __restrict__ wv,
    float* __restrict__ QN, float* __restrict__ KN, float* __restrict__ VV)
{
    __shared__ float sW[3][CC * DKK];
    const int idx = blockIdx.x * 256 + threadIdx.x;   // bh*NN + n
    const int bh  = idx >> 12;
    const int n   = idx & (NN - 1);
    const int b   = bh >> 2;
    const int h   = bh & 3;

    const int hbase = h * CC * DKK;
    for (int i = threadIdx.x; i < CC * DKK; i += 256) {
        sW[0][i] = wq[hbase + i] * 0.125f;
        sW[1][i] = wk[hbase + i] * 0.125f;
        sW[2][i] = wv[hbase + i] * 0.125f;
    }
    __syncthreads();

    float aq[DKK] = {}, ak[DKK] = {}, av[DKK] = {};
    const float* xb = x + (size_t)b * CC * NN + n;
    for (int c = 0; c < CC; ++c) {
        const float xv = xb[(size_t)c * NN];
        const float4* q4 = (const float4*)(sW[0] + c * DKK);
        const float4* k4 = (const float4*)(sW[1] + c * DKK);
        const float4* v4 = (const float4*)(sW[2] + c * DKK);
        #pragma unroll
        for (int j = 0; j < 4; ++j) {
            float4 a = q4[j];
            aq[4*j+0] += xv * a.x; aq[4*j+1] += xv * a.y;
            aq[4*j+2] += xv * a.z; aq[4*j+3] += xv * a.w;
            float4 bk = k4[j];
            ak[4*j+0] += xv * bk.x; ak[4*j+1] += xv * bk.y;
            ak[4*j+2] += xv * bk.z; ak[4*j+3] += xv * bk.w;
            float4 cv = v4[j];
            av[4*j+0] += xv * cv.x; av[4*j+1] += xv * cv.y;
            av[4*j+2] += xv * cv.z; av[4*j+3] += xv * cv.w;
        }
    }

    float sq = 0.f, sk = 0.f;
    #pragma unroll
    for (int i = 0; i < DKK; ++i) { sq += aq[i]*aq[i]; sk += ak[i]*ak[i]; }
    const float rq = 1.0f / (sqrtf(sq) + EPSF);
    const float rk = 1.0f / (sqrtf(sk) + EPSF);

    float* qo = QN + ((size_t)bh * NN + n) * DKK;
    float* ko = KN + ((size_t)bh * NN + n) * DKK;
    float* vo = VV + ((size_t)bh * NN + n) * DKK;
    #pragma unroll
    for (int j = 0; j < 4; ++j) {
        ((float4*)qo)[j] = make_float4(aq[4*j+0]*rq, aq[4*j+1]*rq, aq[4*j+2]*rq, aq[4*j+3]*rq);
        ((float4*)ko)[j] = make_float4(ak[4*j+0]*rk, ak[4*j+1]*rk, ak[4*j+2]*rk, ak[4*j+3]*rk);
        ((float4*)vo)[j] = make_float4(av[4*j+0], av[4*j+1], av[4*j+2], av[4*j+3]);
    }
}

// ---------------------------------------------------------------------------
// Stage 2: flash attention partials. One thread per q-row, keys split ksplit
// ways across blocks. K/V row addresses are wave-uniform -> scalar loads.
// Writes (o_unnorm[16], m, l) per (row, split).
// ---------------------------------------------------------------------------
__global__ __launch_bounds__(256) void attn_kernel(
    const float* __restrict__ QN, const float* __restrict__ KN,
    const float* __restrict__ VV, float* __restrict__ PART, int ksplit)
{
    const int bid   = blockIdx.x;
    const int split = bid % ksplit;
    const int qt    = (bid / ksplit) & 15;
    const int bh    = bid / (ksplit * 16);
    const int n     = qt * 256 + threadIdx.x;

    const float* qp = QN + ((size_t)bh * NN + n) * DKK;
    float q[DKK];
    #pragma unroll
    for (int j = 0; j < 4; ++j) {
        float4 t = ((const float4*)qp)[j];
        q[4*j+0] = t.x; q[4*j+1] = t.y; q[4*j+2] = t.z; q[4*j+3] = t.w;
    }
    const float* Kb = KN + (size_t)bh * NN * DKK;
    const float* Vb = VV + (size_t)bh * NN * DKK;

    float o[DKK] = {};
    float mm = -1e30f, l = 0.f;
    const int keys = NN / ksplit;
    const int m0 = split * keys;
    for (int m = m0; m < m0 + keys; ++m) {
        const float4* kp = (const float4*)(Kb + (size_t)m * DKK);
        const float4 k0 = kp[0], k1 = kp[1], k2 = kp[2], k3 = kp[3];
        float s0 = q[0]*k0.x + q[1]*k0.y + q[2]*k0.z + q[3]*k0.w;
        float s1 = q[4]*k1.x + q[5]*k1.y + q[6]*k1.z + q[7]*k1.w;
        float s2 = q[8]*k2.x + q[9]*k2.y + q[10]*k2.z + q[11]*k2.w;
        float s3 = q[12]*k3.x + q[13]*k3.y + q[14]*k3.z + q[15]*k3.w;
        const float s = (s0 + s1) + (s2 + s3);

        const float4* vp = (const float4*)(Vb + (size_t)m * DKK);
        const float4 v0 = vp[0], v1 = vp[1], v2 = vp[2], v3 = vp[3];

        if (__any(s > mm)) {             // wave-wide vote: rescale path is rare
            const float newm = fmaxf(mm, s);
            const float corr = __expf(mm - newm);   // ==1 for lanes w/o update
            l *= corr;
            #pragma unroll
            for (int i = 0; i < DKK; ++i) o[i] *= corr;
            mm = newm;
        }
        const float p = __expf(s - mm);
        l += p;
        o[0]  += p*v0.x; o[1]  += p*v0.y; o[2]  += p*v0.z; o[3]  += p*v0.w;
        o[4]  += p*v1.x; o[5]  += p*v1.y; o[6]  += p*v1.z; o[7]  += p*v1.w;
        o[8]  += p*v2.x; o[9]  += p*v2.y; o[10] += p*v2.z; o[11] += p*v2.w;
        o[12] += p*v3.x; o[13] += p*v3.y; o[14] += p*v3.z; o[15] += p*v3.w;
    }

    float* pp = PART + (((size_t)bh * NN + n) * (size_t)ksplit + split) * 18;
    #pragma unroll
    for (int i = 0; i < DKK; ++i) pp[i] = o[i];
    pp[16] = mm; pp[17] = l;
}

// ---------------------------------------------------------------------------
// Stage 3: combine key-split partials, write O2T[b][h*16+v][n] (transposed so
// stage 4 reads coalesced).
// ---------------------------------------------------------------------------
__global__ __launch_bounds__(256) void combine_kernel(
    const float* __restrict__ PART, float* __restrict__ O2T, int ksplit)
{
    const int idx = blockIdx.x * 256 + threadIdx.x;   // bh*NN + n
    const int bh = idx >> 12;
    const int n  = idx & (NN - 1);
    const int b  = bh >> 2;
    const int h  = bh & 3;

    const float* pp = PART + (size_t)idx * (size_t)ksplit * 18;
    float M = -1e30f;
    for (int s = 0; s < ksplit; ++s) M = fmaxf(M, pp[s*18 + 16]);
    float den = 0.f, num[DKK] = {};
    for (int s = 0; s < ksplit; ++s) {
        const float w = __expf(pp[s*18 + 16] - M);
        den += w * pp[s*18 + 17];
        #pragma unroll
        for (int i = 0; i < DKK; ++i) num[i] += w * pp[s*18 + i];
    }
    const float r = 1.0f / den;
    float* ob = O2T + ((size_t)b * CC + h * DKK) * NN + n;
    #pragma unroll
    for (int i = 0; i < DKK; ++i) ob[(size_t)i * NN] = num[i] * r;
}

// ---------------------------------------------------------------------------
// Stage 4: y[b,c,n] = sum_{h,v} o[b,h,n,v] * wo[h,c,v] / 8. Coalesced reads
// of O2T, wave-uniform weight reads.
// ---------------------------------------------------------------------------
__global__ __launch_bounds__(256) void out_kernel(
    const float* __restrict__ O2T, const float* __restrict__ wo,
    float* __restrict__ y)
{
    const int idx = blockIdx.x * 256 + threadIdx.x;   // (b*CC + c)*NN + n
    const int n  = idx & (NN - 1);
    const int bc = idx >> 12;
    const int c  = bc & (CC - 1);
    const int b  = bc >> 6;

    const float* ob = O2T + (size_t)b * CC * NN + n;
    float acc = 0.f;
    #pragma unroll
    for (int h = 0; h < NHEADS; ++h) {
        const float* wrow = wo + ((size_t)h * CC + c) * DKK;
        #pragma unroll
        for (int v = 0; v < DKK; ++v)
            acc += ob[(size_t)(h * DKK + v) * NN] * wrow[v];
    }
    y[idx] = acc * 0.125f;
}

// ---------------------------------------------------------------------------
extern "C" void kernel_launch(void* const* d_in, const int* in_sizes, int n_in,
                              void* d_out, int out_size, void* d_ws, size_t ws_size,
                              hipStream_t stream)
{
    const float* x  = (const float*)d_in[0];
    const float* wq = (const float*)d_in[1];
    const float* wk = (const float*)d_in[2];
    const float* wv = (const float*)d_in[3];
    const float* wo = (const float*)d_in[4];
    float* y = (float*)d_out;

    float* ws = (float*)d_ws;
    const size_t QKV = (size_t)BB * NHEADS * NN * DKK;   // 524288 floats

    int ksplit = 4;
    {
        const size_t need = (3*QKV + (size_t)BB*NHEADS*NN*(size_t)ksplit*18
                             + (size_t)BB*CC*NN) * sizeof(float);
        if (need > ws_size) ksplit = 1;
    }

    float* QN   = ws;
    float* KN   = ws + QKV;
    float* VV   = ws + 2*QKV;
    float* PART = ws + 3*QKV;
    float* O2T  = PART + (size_t)BB*NHEADS*NN*(size_t)ksplit*18;

    proj_kernel<<<(BB*NHEADS*NN)/256, 256, 0, stream>>>(x, wq, wk, wv, QN, KN, VV);
    attn_kernel<<<BB*NHEADS*16*ksplit, 256, 0, stream>>>(QN, KN, VV, PART, ksplit);
    combine_kernel<<<(BB*NHEADS*NN)/256, 256, 0, stream>>>(PART, O2T, ksplit);
    out_kernel<<<(BB*CC*NN)/256, 256, 0, stream>>>(O2T, wo, y);
}

// Round 2
// 181.478 us; speedup vs baseline: 3.0643x; 3.0643x over previous
//
#include <hip/hip_runtime.h>
#include <math.h>

#define NHEADS 4
#define DKK 16
#define CC 64
#define BB 2
#define NN 4096
#define NBH 8
#define EPSF 1e-8f
#define KSPLIT 4
#define PARTSTRIDE 272   // 256 o^T + 16 l

typedef __attribute__((ext_vector_type(8))) short bf8;
typedef __attribute__((ext_vector_type(4))) float f4;

union Frag { bf8 v; struct { uint2 lo, hi; } p; };

__device__ __forceinline__ unsigned short f2bf(float f) {
    union { float f; unsigned int u; } v; v.f = f;
    unsigned int r = v.u + 0x7FFFu + ((v.u >> 16) & 1u);   // RNE
    return (unsigned short)(r >> 16);
}
__device__ __forceinline__ float bf2f(unsigned short h) {
    union { unsigned int u; float f; } v; v.u = ((unsigned int)h) << 16;
    return v.f;
}

// ---------------------------------------------------------------------------
// Stage 1: projections + normalize + hi/lo bf16 split. Writes Q_hi/Q_lo,
// K_hi/K_lo as [bh][n][16] bf16 and V^T_hi/V^T_lo as [bh][16][n] bf16.
// ---------------------------------------------------------------------------
__global__ __launch_bounds__(256) void proj_kernel(
    const float* __restrict__ x, const float* __restrict__ wq,
    const float* __restrict__ wk, const float* __restrict__ wv,
    unsigned short* __restrict__ Qh, unsigned short* __restrict__ Ql,
    unsigned short* __restrict__ Kh, unsigned short* __restrict__ Kl,
    unsigned short* __restrict__ VTh, unsigned short* __restrict__ VTl)
{
    __shared__ float sW[3][CC * DKK];
    const int idx = blockIdx.x * 256 + threadIdx.x;   // bh*NN + n
    const int bh  = idx >> 12;
    const int n   = idx & (NN - 1);
    const int b   = bh >> 2;
    const int h   = bh & 3;

    const int hbase = h * CC * DKK;
    for (int i = threadIdx.x; i < CC * DKK; i += 256) {
        sW[0][i] = wq[hbase + i] * 0.125f;
        sW[1][i] = wk[hbase + i] * 0.125f;
        sW[2][i] = wv[hbase + i] * 0.125f;
    }
    __syncthreads();

    float aq[DKK] = {}, ak[DKK] = {}, av[DKK] = {};
    const float* xb = x + (size_t)b * CC * NN + n;
    for (int c = 0; c < CC; ++c) {
        const float xv = xb[(size_t)c * NN];
        const float4* q4 = (const float4*)(sW[0] + c * DKK);
        const float4* k4 = (const float4*)(sW[1] + c * DKK);
        const float4* v4 = (const float4*)(sW[2] + c * DKK);
        #pragma unroll
        for (int j = 0; j < 4; ++j) {
            float4 a = q4[j];
            aq[4*j+0] += xv * a.x; aq[4*j+1] += xv * a.y;
            aq[4*j+2] += xv * a.z; aq[4*j+3] += xv * a.w;
            float4 bk = k4[j];
            ak[4*j+0] += xv * bk.x; ak[4*j+1] += xv * bk.y;
            ak[4*j+2] += xv * bk.z; ak[4*j+3] += xv * bk.w;
            float4 cv = v4[j];
            av[4*j+0] += xv * cv.x; av[4*j+1] += xv * cv.y;
            av[4*j+2] += xv * cv.z; av[4*j+3] += xv * cv.w;
        }
    }

    float sq = 0.f, sk = 0.f;
    #pragma unroll
    for (int i = 0; i < DKK; ++i) { sq += aq[i]*aq[i]; sk += ak[i]*ak[i]; }
    const float rq = 1.0f / (sqrtf(sq) + EPSF);
    const float rk = 1.0f / (sqrtf(sk) + EPSF);

    __attribute__((aligned(16))) unsigned short qh[DKK], ql[DKK], kh[DKK], kl[DKK];
    #pragma unroll
    for (int i = 0; i < DKK; ++i) {
        const float qv = aq[i] * rq;
        unsigned short hq = f2bf(qv);
        qh[i] = hq; ql[i] = f2bf(qv - bf2f(hq));
        const float kv = ak[i] * rk;
        unsigned short hk = f2bf(kv);
        kh[i] = hk; kl[i] = f2bf(kv - bf2f(hk));
    }
    const size_t base = ((size_t)bh * NN + n) * DKK;
    ((uint4*)(Qh + base))[0] = ((const uint4*)qh)[0];
    ((uint4*)(Qh + base))[1] = ((const uint4*)qh)[1];
    ((uint4*)(Ql + base))[0] = ((const uint4*)ql)[0];
    ((uint4*)(Ql + base))[1] = ((const uint4*)ql)[1];
    ((uint4*)(Kh + base))[0] = ((const uint4*)kh)[0];
    ((uint4*)(Kh + base))[1] = ((const uint4*)kh)[1];
    ((uint4*)(Kl + base))[0] = ((const uint4*)kl)[0];
    ((uint4*)(Kl + base))[1] = ((const uint4*)kl)[1];

    const size_t vbase = (size_t)bh * DKK * NN + n;
    #pragma unroll
    for (int i = 0; i < DKK; ++i) {
        const float vv = av[i];
        unsigned short hv = f2bf(vv);
        VTh[vbase + (size_t)i * NN] = hv;
        VTl[vbase + (size_t)i * NN] = f2bf(vv - bf2f(hv));
    }
}

// ---------------------------------------------------------------------------
// Stage 2: MFMA attention partials. Per wave: 16 q-rows x 1024 keys (split 4).
// S^T = mfma(K, Q) hi/lo-split; p = exp(s) (no max needed: s <= 1);
// o^T = mfma([V^T_hi|V^T_lo], [P^T|P^T]) -- shuffle-free (C rows == B k-slots).
// ---------------------------------------------------------------------------
__global__ __launch_bounds__(256) void attn_kernel(
    const unsigned short* __restrict__ Qh, const unsigned short* __restrict__ Ql,
    const unsigned short* __restrict__ Kh, const unsigned short* __restrict__ Kl,
    const unsigned short* __restrict__ VTh, const unsigned short* __restrict__ VTl,
    float* __restrict__ PART)
{
    const int bid   = blockIdx.x;
    const int bh    = bid >> 8;           // 8
    const int split = (bid >> 6) & 3;     // 4
    const int qg    = bid & 63;           // 64 groups of 4 qblocks
    const int wave  = threadIdx.x >> 6;
    const int lane  = threadIdx.x & 63;
    const int qblock = qg * 4 + wave;     // [0,256)
    const int g = lane >> 4;
    const int r = lane & 15;

    // Q B-frags: col=r=q, k-slots j0..3 -> dk g*4+j, j4..7 dup
    const size_t qoff = ((size_t)bh * NN + qblock * 16 + r) * DKK + g * 4;
    Frag qhB, qlB;
    qhB.p.lo = *(const uint2*)(Qh + qoff); qhB.p.hi = qhB.p.lo;
    qlB.p.lo = *(const uint2*)(Ql + qoff); qlB.p.hi = qlB.p.lo;

    const int key0 = split * (NN / KSPLIT);
    const unsigned short* kh_p = Kh + ((size_t)bh * NN + key0 + r) * DKK + g * 4;
    const unsigned short* kl_p = Kl + ((size_t)bh * NN + key0 + r) * DKK + g * 4;
    const unsigned short* vh_p = VTh + ((size_t)bh * DKK + r) * NN + key0 + g * 4;
    const unsigned short* vl_p = VTl + ((size_t)bh * DKK + r) * NN + key0 + g * 4;

    f4 oC = {0.f, 0.f, 0.f, 0.f};
    const f4 zero = {0.f, 0.f, 0.f, 0.f};
    float l_acc = 0.f;

    for (int t = 0; t < (NN / KSPLIT) / 16; ++t) {
        Frag kA1, kA2, vA, pB;
        kA1.p.lo = *(const uint2*)kh_p;       // k_hi, dk g*4..+3
        kA1.p.hi = *(const uint2*)kl_p;       // k_lo
        kA2.p.lo = kA1.p.lo;                  // [k_hi | 0]
        kA2.p.hi = make_uint2(0u, 0u);

        f4 s = __builtin_amdgcn_mfma_f32_16x16x32_bf16(kA2.v, qlB.v, zero, 0, 0, 0);
        s     = __builtin_amdgcn_mfma_f32_16x16x32_bf16(kA1.v, qhB.v, s,    0, 0, 0);

        // lane holds S^T[key=g*4+reg][q=r]; p = exp(s), s <= 1 so stable
        const float p0 = __expf(s[0]), p1 = __expf(s[1]);
        const float p2 = __expf(s[2]), p3 = __expf(s[3]);
        l_acc += (p0 + p1) + (p2 + p3);

        unsigned int u0, u1;
        asm("v_cvt_pk_bf16_f32 %0, %1, %2" : "=v"(u0) : "v"(p0), "v"(p1));
        asm("v_cvt_pk_bf16_f32 %0, %1, %2" : "=v"(u1) : "v"(p2), "v"(p3));
        pB.p.lo = make_uint2(u0, u1); pB.p.hi = pB.p.lo;   // [P^T | P^T]

        vA.p.lo = *(const uint2*)vh_p;        // V^T_hi keys g*4..+3
        vA.p.hi = *(const uint2*)vl_p;        // V^T_lo same keys

        oC = __builtin_amdgcn_mfma_f32_16x16x32_bf16(vA.v, pB.v, oC, 0, 0, 0);

        kh_p += 16 * DKK; kl_p += 16 * DKK; vh_p += 16; vl_p += 16;
    }

    // l_acc: partial rowsum for q=r over this lane's key groups; reduce 4 groups
    l_acc += __shfl_xor(l_acc, 16);
    l_acc += __shfl_xor(l_acc, 32);

    float* pp = PART + (((size_t)bh * 256 + qblock) * KSPLIT + split) * PARTSTRIDE;
    #pragma unroll
    for (int i = 0; i < 4; ++i) pp[(g * 4 + i) * 16 + r] = oC[i];  // o^T[dv][q]
    if (g == 0) pp[256 + r] = l_acc;
}

// ---------------------------------------------------------------------------
// Stage 3: combine split partials (plain sums -- no max), write O2T[b][h*16+dv][n]
// ---------------------------------------------------------------------------
__global__ __launch_bounds__(256) void combine_kernel(
    const float* __restrict__ PART, float* __restrict__ O2T)
{
    const int idx = blockIdx.x * 256 + threadIdx.x;   // bh*NN + n
    const int bh = idx >> 12;
    const int n  = idx & (NN - 1);
    const int qb = n >> 4;
    const int q  = n & 15;
    const int b  = bh >> 2;
    const int h  = bh & 3;

    const float* pp = PART + ((size_t)bh * 256 + qb) * KSPLIT * PARTSTRIDE;
    float den = 0.f;
    #pragma unroll
    for (int s = 0; s < KSPLIT; ++s) den += pp[s * PARTSTRIDE + 256 + q];
    const float rd = 1.0f / den;

    float* ob = O2T + ((size_t)b * CC + h * DKK) * NN + n;
    #pragma unroll
    for (int dv = 0; dv < DKK; ++dv) {
        float num = 0.f;
        #pragma unroll
        for (int s = 0; s < KSPLIT; ++s) num += pp[s * PARTSTRIDE + dv * 16 + q];
        ob[(size_t)dv * NN] = num * rd;
    }
}

// ---------------------------------------------------------------------------
// Stage 4: y[b,c,n] = sum_{h,v} o[b,h,n,v] * wo[h,c,v] / 8
// ---------------------------------------------------------------------------
__global__ __launch_bounds__(256) void out_kernel(
    const float* __restrict__ O2T, const float* __restrict__ wo,
    float* __restrict__ y)
{
    const int idx = blockIdx.x * 256 + threadIdx.x;   // (b*CC + c)*NN + n
    const int n  = idx & (NN - 1);
    const int bc = idx >> 12;
    const int c  = bc & (CC - 1);
    const int b  = bc >> 6;

    const float* ob = O2T + (size_t)b * CC * NN + n;
    float acc = 0.f;
    #pragma unroll
    for (int h = 0; h < NHEADS; ++h) {
        const float* wrow = wo + ((size_t)h * CC + c) * DKK;
        #pragma unroll
        for (int v = 0; v < DKK; ++v)
            acc += ob[(size_t)(h * DKK + v) * NN] * wrow[v];
    }
    y[idx] = acc * 0.125f;
}

// ---------------------------------------------------------------------------
extern "C" void kernel_launch(void* const* d_in, const int* in_sizes, int n_in,
                              void* d_out, int out_size, void* d_ws, size_t ws_size,
                              hipStream_t stream)
{
    const float* x  = (const float*)d_in[0];
    const float* wq = (const float*)d_in[1];
    const float* wk = (const float*)d_in[2];
    const float* wv = (const float*)d_in[3];
    const float* wo = (const float*)d_in[4];
    float* y = (float*)d_out;

    const size_t QE = (size_t)NBH * NN * DKK;   // 524288 bf16 elems per buffer
    unsigned short* Qh  = (unsigned short*)d_ws;
    unsigned short* Ql  = Qh + QE;
    unsigned short* Kh  = Qh + 2 * QE;
    unsigned short* Kl  = Qh + 3 * QE;
    unsigned short* VTh = Qh + 4 * QE;
    unsigned short* VTl = Qh + 5 * QE;
    float* PART = (float*)(Qh + 6 * QE);
    float* O2T  = PART + (size_t)NBH * 256 * KSPLIT * PARTSTRIDE;

    proj_kernel<<<(NBH * NN) / 256, 256, 0, stream>>>(x, wq, wk, wv,
                                                      Qh, Ql, Kh, Kl, VTh, VTl);
    attn_kernel<<<NBH * KSPLIT * 64, 256, 0, stream>>>(Qh, Ql, Kh, Kl, VTh, VTl, PART);
    combine_kernel<<<(NBH * NN) / 256, 256, 0, stream>>>(PART, O2T);
    out_kernel<<<(BB * CC * NN) / 256, 256, 0, stream>>>(O2T, wo, y);
}

// Round 4
// 89.283 us; speedup vs baseline: 6.2285x; 2.0326x over previous
//
#include <hip/hip_runtime.h>
#include <math.h>

#define NHEADS 4
#define DKK 16
#define CC 64
#define BB 2
#define NN 4096
#define NBH 8
#define EPSF 1e-8f
#define KSPLIT 4
#define PARTSTRIDE 272   // 256 o^T + 16 l
#define LOG2E 1.44269504088896340736f

typedef __attribute__((ext_vector_type(8))) short bf8;
typedef __attribute__((ext_vector_type(4))) float f4;

union Frag { bf8 v; struct { uint2 lo, hi; } p; uint4 q; };

__device__ __forceinline__ unsigned short f2bf(float f) {
    union { float f; unsigned int u; } v; v.f = f;
    unsigned int r = v.u + 0x7FFFu + ((v.u >> 16) & 1u);   // RNE
    return (unsigned short)(r >> 16);
}
__device__ __forceinline__ float bf2f(unsigned short h) {
    union { unsigned int u; float f; } v; v.u = ((unsigned int)h) << 16;
    return v.f;
}

// ---------------------------------------------------------------------------
// Stage 0: zero the entire used workspace so every call (first validation AND
// every graph replay) starts from identical ws state -> deterministic output.
// Plain stores (no hipMemsetAsync) to be 100% graph-capture-safe.
// ---------------------------------------------------------------------------
__global__ __launch_bounds__(256) void zerofill_kernel(uint4* __restrict__ p,
                                                       unsigned int count16)
{
    const uint4 z = make_uint4(0u, 0u, 0u, 0u);
    const unsigned int stride = gridDim.x * 256;
    for (unsigned int i = blockIdx.x * 256 + threadIdx.x; i < count16; i += stride)
        p[i] = z;
}

// ---------------------------------------------------------------------------
// Stage 1: projections + normalize + hi/lo bf16 split, interleaved layouts.
// QP/KP[bh][n][32]: [g*8+j] = hi[g*4+j], [g*8+4+j] = lo[g*4+j]  (Q scaled by
// log2e so stage 2 uses exp2 directly).
// VP[bh][dv(16)][tile(256)][32]: [g*8+j] = hi of key tile*16+g*4+j, +4 = lo.
// ---------------------------------------------------------------------------
__global__ __launch_bounds__(64) void proj_kernel(
    const float* __restrict__ x, const float* __restrict__ wq,
    const float* __restrict__ wk, const float* __restrict__ wv,
    unsigned short* __restrict__ QP, unsigned short* __restrict__ KP,
    unsigned short* __restrict__ VP)
{
    __shared__ float sW[3 * CC * DKK];
    const int bh = blockIdx.x >> 6;
    const int n  = (blockIdx.x & 63) * 64 + threadIdx.x;
    const int b  = bh >> 2;
    const int h  = bh & 3;

    const int hbase = h * CC * DKK;
    for (int i = threadIdx.x; i < CC * DKK; i += 64) {
        sW[i]                 = wq[hbase + i] * 0.125f;
        sW[CC * DKK + i]      = wk[hbase + i] * 0.125f;
        sW[2 * CC * DKK + i]  = wv[hbase + i] * 0.125f;
    }
    __syncthreads();

    float aq[DKK] = {}, ak[DKK] = {}, av[DKK] = {};
    const float* xb = x + (size_t)b * CC * NN + n;
    for (int c = 0; c < CC; ++c) {
        const float xv = xb[(size_t)c * NN];
        const float4* q4 = (const float4*)(sW + c * DKK);
        const float4* k4 = (const float4*)(sW + CC * DKK + c * DKK);
        const float4* v4 = (const float4*)(sW + 2 * CC * DKK + c * DKK);
        #pragma unroll
        for (int j = 0; j < 4; ++j) {
            float4 a = q4[j];
            aq[4*j+0] += xv * a.x; aq[4*j+1] += xv * a.y;
            aq[4*j+2] += xv * a.z; aq[4*j+3] += xv * a.w;
            float4 bk = k4[j];
            ak[4*j+0] += xv * bk.x; ak[4*j+1] += xv * bk.y;
            ak[4*j+2] += xv * bk.z; ak[4*j+3] += xv * bk.w;
            float4 cv = v4[j];
            av[4*j+0] += xv * cv.x; av[4*j+1] += xv * cv.y;
            av[4*j+2] += xv * cv.z; av[4*j+3] += xv * cv.w;
        }
    }

    float sq = 0.f, sk = 0.f;
    #pragma unroll
    for (int i = 0; i < DKK; ++i) { sq += aq[i]*aq[i]; sk += ak[i]*ak[i]; }
    const float rq = LOG2E / (sqrtf(sq) + EPSF);   // log2e folded into Q
    const float rk = 1.0f / (sqrtf(sk) + EPSF);

    __attribute__((aligned(16))) unsigned short qp[32], kp[32];
    #pragma unroll
    for (int g = 0; g < 4; ++g) {
        #pragma unroll
        for (int j = 0; j < 4; ++j) {
            const float qv = aq[g*4+j] * rq;
            unsigned short hq = f2bf(qv);
            qp[g*8+j]   = hq;
            qp[g*8+4+j] = f2bf(qv - bf2f(hq));
            const float kv = ak[g*4+j] * rk;
            unsigned short hk = f2bf(kv);
            kp[g*8+j]   = hk;
            kp[g*8+4+j] = f2bf(kv - bf2f(hk));
        }
    }
    const size_t base = ((size_t)bh * NN + n) * 32;
    #pragma unroll
    for (int j = 0; j < 4; ++j) {
        ((uint4*)(QP + base))[j] = ((const uint4*)qp)[j];
        ((uint4*)(KP + base))[j] = ((const uint4*)kp)[j];
    }

    // VP scatter: tile = n/16, g = (n%16)/4, slot = n%4
    const size_t vbase = (((size_t)bh * DKK) * 256 + (n >> 4)) * 32
                         + ((n >> 2) & 3) * 8 + (n & 3);
    #pragma unroll
    for (int i = 0; i < DKK; ++i) {
        const float vv = av[i];
        unsigned short hv = f2bf(vv);
        VP[vbase + (size_t)i * 256 * 32]     = hv;
        VP[vbase + (size_t)i * 256 * 32 + 4] = f2bf(vv - bf2f(hv));
    }
}

// ---------------------------------------------------------------------------
// One 16-key tile of the attention inner loop (6 MFMA, 8 exp2).
// ---------------------------------------------------------------------------
__device__ __forceinline__ void attn_tile(
    const Frag& kc, const Frag& vc,
    const Frag& qahB, const Frag& qalB, const Frag& qbhB, const Frag& qblB,
    f4& oCa, f4& oCb, float& la, float& lb)
{
    const f4 zero = {0.f, 0.f, 0.f, 0.f};
    Frag kA2;                              // [K_hi | 0]
    kA2.p.lo = kc.p.lo; kA2.p.hi = make_uint2(0u, 0u);

    f4 sa = __builtin_amdgcn_mfma_f32_16x16x32_bf16(kA2.v, qalB.v, zero, 0, 0, 0);
    sa    = __builtin_amdgcn_mfma_f32_16x16x32_bf16(kc.v,  qahB.v, sa,   0, 0, 0);
    f4 sb = __builtin_amdgcn_mfma_f32_16x16x32_bf16(kA2.v, qblB.v, zero, 0, 0, 0);
    sb    = __builtin_amdgcn_mfma_f32_16x16x32_bf16(kc.v,  qbhB.v, sb,   0, 0, 0);

    const float pa0 = __builtin_amdgcn_exp2f(sa[0]), pa1 = __builtin_amdgcn_exp2f(sa[1]);
    const float pa2 = __builtin_amdgcn_exp2f(sa[2]), pa3 = __builtin_amdgcn_exp2f(sa[3]);
    const float pb0 = __builtin_amdgcn_exp2f(sb[0]), pb1 = __builtin_amdgcn_exp2f(sb[1]);
    const float pb2 = __builtin_amdgcn_exp2f(sb[2]), pb3 = __builtin_amdgcn_exp2f(sb[3]);
    la += (pa0 + pa1) + (pa2 + pa3);
    lb += (pb0 + pb1) + (pb2 + pb3);

    unsigned int ua0, ua1, ub0, ub1;
    asm("v_cvt_pk_bf16_f32 %0, %1, %2" : "=v"(ua0) : "v"(pa0), "v"(pa1));
    asm("v_cvt_pk_bf16_f32 %0, %1, %2" : "=v"(ua1) : "v"(pa2), "v"(pa3));
    asm("v_cvt_pk_bf16_f32 %0, %1, %2" : "=v"(ub0) : "v"(pb0), "v"(pb1));
    asm("v_cvt_pk_bf16_f32 %0, %1, %2" : "=v"(ub1) : "v"(pb2), "v"(pb3));
    Frag pBa, pBb;
    pBa.p.lo = make_uint2(ua0, ua1); pBa.p.hi = pBa.p.lo;
    pBb.p.lo = make_uint2(ub0, ub1); pBb.p.hi = pBb.p.lo;

    oCa = __builtin_amdgcn_mfma_f32_16x16x32_bf16(vc.v, pBa.v, oCa, 0, 0, 0);
    oCb = __builtin_amdgcn_mfma_f32_16x16x32_bf16(vc.v, pBb.v, oCb, 0, 0, 0);
}

// ---------------------------------------------------------------------------
// Stage 2: MFMA attention partials. 1024 blocks x 4 waves; wave = 2 q-frags
// (32 q-rows) x 1024 keys. Per 16-key tile: one dwordx4 each for K and V
// (hi/lo interleaved). Prefetch-1 pipeline with the LAST tile peeled so no
// load ever goes past the valid data (R3's OOB prefetch caused replay
// divergence). XCD-chunked swizzle for K/V L2 locality.
// ---------------------------------------------------------------------------
__global__ __launch_bounds__(256, 4) void attn_kernel(
    const unsigned short* __restrict__ QP, const unsigned short* __restrict__ KP,
    const unsigned short* __restrict__ VP, float* __restrict__ PART)
{
    const int orig  = (blockIdx.x & 7) * 128 + (blockIdx.x >> 3);  // XCD chunk
    const int bh    = orig >> 7;
    const int split = (orig >> 5) & 3;
    const int qg    = orig & 31;
    const int wave  = threadIdx.x >> 6;
    const int lane  = threadIdx.x & 63;
    const int qb    = qg * 8 + wave * 2;        // this wave: qblocks qb, qb+1
    const int g = lane >> 4;
    const int r = lane & 15;

    // Q frags: one 16B load each -> [hi(4) | lo(4)]
    const size_t qoff = ((size_t)bh * NN + qb * 16 + r) * 32 + g * 8;
    Frag qa, qbf;
    qa.q  = *(const uint4*)(QP + qoff);
    qbf.q = *(const uint4*)(QP + qoff + 16 * 32);
    Frag qahB, qalB, qbhB, qblB;
    qahB.p.lo = qa.p.lo;  qahB.p.hi = qa.p.lo;
    qalB.p.lo = qa.p.hi;  qalB.p.hi = qa.p.hi;
    qbhB.p.lo = qbf.p.lo; qbhB.p.hi = qbf.p.lo;
    qblB.p.lo = qbf.p.hi; qblB.p.hi = qbf.p.hi;

    const int key0 = split * (NN / KSPLIT);
    const unsigned short* kp_p = KP + ((size_t)bh * NN + key0 + r) * 32 + g * 8;
    const unsigned short* vp_p = VP + (((size_t)bh * DKK + r) * 256 + (key0 >> 4)) * 32 + g * 8;

    f4 oCa = {0.f,0.f,0.f,0.f}, oCb = {0.f,0.f,0.f,0.f};
    float la = 0.f, lb = 0.f;

    Frag kc, vc;
    kc.q = *(const uint4*)kp_p;
    vc.q = *(const uint4*)vp_p;

    for (int t = 0; t < 63; ++t) {          // prefetch tiles 1..63: all valid
        Frag kn, vn;
        kn.q = *(const uint4*)(kp_p + 512);
        vn.q = *(const uint4*)(vp_p + 32);
        kp_p += 512; vp_p += 32;

        attn_tile(kc, vc, qahB, qalB, qbhB, qblB, oCa, oCb, la, lb);

        kc = kn; vc = vn;
    }
    attn_tile(kc, vc, qahB, qalB, qbhB, qblB, oCa, oCb, la, lb);  // tile 63

    la += __shfl_xor(la, 16); la += __shfl_xor(la, 32);
    lb += __shfl_xor(lb, 16); lb += __shfl_xor(lb, 32);

    float* ppa = PART + (((size_t)bh * 256 + qb) * KSPLIT + split) * PARTSTRIDE;
    float* ppb = ppa + KSPLIT * PARTSTRIDE;
    #pragma unroll
    for (int i = 0; i < 4; ++i) {
        ppa[(g * 4 + i) * 16 + r] = oCa[i];
        ppb[(g * 4 + i) * 16 + r] = oCb[i];
    }
    if (g == 0) { ppa[256 + r] = la; ppb[256 + r] = lb; }
}

// ---------------------------------------------------------------------------
// Stage 3: combine split partials (plain sums), write O2T[b][h*16+dv][n].
// ---------------------------------------------------------------------------
__global__ __launch_bounds__(64) void combine_kernel(
    const float* __restrict__ PART, float* __restrict__ O2T)
{
    const int idx = blockIdx.x * 64 + threadIdx.x;   // bh*NN + n
    const int bh = idx >> 12;
    const int n  = idx & (NN - 1);
    const int qb = n >> 4;
    const int q  = n & 15;
    const int b  = bh >> 2;
    const int h  = bh & 3;

    const float* pp = PART + ((size_t)bh * 256 + qb) * KSPLIT * PARTSTRIDE;
    float den = 0.f;
    #pragma unroll
    for (int s = 0; s < KSPLIT; ++s) den += pp[s * PARTSTRIDE + 256 + q];
    const float rd = 1.0f / den;

    float* ob = O2T + ((size_t)b * CC + h * DKK) * NN + n;
    #pragma unroll
    for (int dv = 0; dv < DKK; ++dv) {
        float num = 0.f;
        #pragma unroll
        for (int s = 0; s < KSPLIT; ++s) num += pp[s * PARTSTRIDE + dv * 16 + q];
        ob[(size_t)dv * NN] = num * rd;
    }
}

// ---------------------------------------------------------------------------
// Stage 4: y[b,c,n] = sum_{h,v} o[b,h,n,v] * wo[h,c,v] / 8
// ---------------------------------------------------------------------------
__global__ __launch_bounds__(256) void out_kernel(
    const float* __restrict__ O2T, const float* __restrict__ wo,
    float* __restrict__ y)
{
    const int idx = blockIdx.x * 256 + threadIdx.x;   // (b*CC + c)*NN + n
    const int n  = idx & (NN - 1);
    const int bc = idx >> 12;
    const int c  = bc & (CC - 1);
    const int b  = bc >> 6;

    const float* ob = O2T + (size_t)b * CC * NN + n;
    float acc = 0.f;
    #pragma unroll
    for (int h = 0; h < NHEADS; ++h) {
        const float* wrow = wo + ((size_t)h * CC + c) * DKK;
        #pragma unroll
        for (int v = 0; v < DKK; ++v)
            acc += ob[(size_t)(h * DKK + v) * NN] * wrow[v];
    }
    y[idx] = acc * 0.125f;
}

// ---------------------------------------------------------------------------
extern "C" void kernel_launch(void* const* d_in, const int* in_sizes, int n_in,
                              void* d_out, int out_size, void* d_ws, size_t ws_size,
                              hipStream_t stream)
{
    const float* x  = (const float*)d_in[0];
    const float* wq = (const float*)d_in[1];
    const float* wk = (const float*)d_in[2];
    const float* wv = (const float*)d_in[3];
    const float* wo = (const float*)d_in[4];
    float* y = (float*)d_out;

    const size_t QE = (size_t)NBH * NN * 32;            // 1M elems per buffer
    const size_t PADE = 1024;                           // 2KB pad
    unsigned short* QP = (unsigned short*)d_ws;
    unsigned short* KP = QP + QE;
    unsigned short* VP = KP + QE + PADE;
    float* PART = (float*)(VP + QE + PADE);
    float* O2T  = PART + (size_t)NBH * 256 * KSPLIT * PARTSTRIDE;

    // total used bytes (multiple of 16)
    const size_t used_bytes = (3 * QE + 2 * PADE) * sizeof(unsigned short)
        + ((size_t)NBH * 256 * KSPLIT * PARTSTRIDE + (size_t)BB * CC * NN) * sizeof(float);

    zerofill_kernel<<<2048, 256, 0, stream>>>((uint4*)d_ws,
                                              (unsigned int)(used_bytes / 16));
    proj_kernel<<<NBH * 64, 64, 0, stream>>>(x, wq, wk, wv, QP, KP, VP);
    attn_kernel<<<NBH * KSPLIT * 32, 256, 0, stream>>>(QP, KP, VP, PART);
    combine_kernel<<<(NBH * NN) / 64, 64, 0, stream>>>(PART, O2T);
    out_kernel<<<(BB * CC * NN) / 256, 256, 0, stream>>>(O2T, wo, y);
}

// Round 5
// 76.380 us; speedup vs baseline: 7.2807x; 1.1689x over previous
//
#include <hip/hip_runtime.h>
#include <math.h>

#define NHEADS 4
#define DKK 16
#define CC 64
#define BB 2
#define NN 4096
#define NBH 8
#define EPSF 1e-8f
#define KSPLIT 8
#define TILES 32          // (NN/KSPLIT)/16 keys per wave
#define LOG2E 1.44269504088896340736f

typedef __attribute__((ext_vector_type(8))) short bf8;
typedef __attribute__((ext_vector_type(4))) float f4;

union Frag { bf8 v; struct { uint2 lo, hi; } p; uint4 q; };

__device__ __forceinline__ unsigned short f2bf(float f) {
    union { float f; unsigned int u; } v; v.f = f;
    unsigned int r = v.u + 0x7FFFu + ((v.u >> 16) & 1u);   // RNE
    return (unsigned short)(r >> 16);
}
__device__ __forceinline__ float bf2f(unsigned short h) {
    union { unsigned int u; float f; } v; v.u = ((unsigned int)h) << 16;
    return v.f;
}

// ---------------------------------------------------------------------------
// Stage 0: zero the used workspace so every call (first validation AND every
// graph replay) starts from identical ws state -> deterministic output.
// ---------------------------------------------------------------------------
__global__ __launch_bounds__(256) void zerofill_kernel(uint4* __restrict__ p,
                                                       unsigned int count16)
{
    const uint4 z = make_uint4(0u, 0u, 0u, 0u);
    const unsigned int stride = gridDim.x * 256;
    for (unsigned int i = blockIdx.x * 256 + threadIdx.x; i < count16; i += stride)
        p[i] = z;
}

// ---------------------------------------------------------------------------
// Stage 1: projections + normalize + hi/lo bf16 split, interleaved layouts.
// c-reduction split 4 ways across lane groups (cq = lane>>4), combined with
// __shfl_xor(16/32) -> 2048 waves (8/CU) instead of 512 (2/CU).
// QP/KP[bh][n][32]: [g*8+j]=hi[g*4+j], [g*8+4+j]=lo[g*4+j] (Q scaled log2e).
// VP[bh][dv(16)][tile(256)][32]: [g*8+j]=hi of key tile*16+g*4+j, +4 = lo.
// ---------------------------------------------------------------------------
__global__ __launch_bounds__(256) void proj_kernel(
    const float* __restrict__ x, const float* __restrict__ wq,
    const float* __restrict__ wk, const float* __restrict__ wv,
    unsigned short* __restrict__ QP, unsigned short* __restrict__ KP,
    unsigned short* __restrict__ VP)
{
    __shared__ float sW[3 * CC * DKK];
    const int bh = blockIdx.x >> 6;
    const int n0 = (blockIdx.x & 63) * 64;
    const int b  = bh >> 2;
    const int h  = bh & 3;

    const int hbase = h * CC * DKK;
    for (int i = threadIdx.x; i < CC * DKK; i += 256) {
        sW[i]                = wq[hbase + i] * 0.125f;
        sW[CC * DKK + i]     = wk[hbase + i] * 0.125f;
        sW[2 * CC * DKK + i] = wv[hbase + i] * 0.125f;
    }
    __syncthreads();

    const int lane = threadIdx.x & 63;
    const int wave = threadIdx.x >> 6;
    const int n  = n0 + wave * 16 + (lane & 15);
    const int cq = lane >> 4;                     // this lane's c-quarter

    float aq[DKK] = {}, ak[DKK] = {}, av[DKK] = {};
    const float* xb = x + (size_t)b * CC * NN + n;
    for (int cc = 0; cc < 16; ++cc) {
        const int c = cq * 16 + cc;
        const float xv = xb[(size_t)c * NN];
        const float4* q4 = (const float4*)(sW + c * DKK);
        const float4* k4 = (const float4*)(sW + CC * DKK + c * DKK);
        const float4* v4 = (const float4*)(sW + 2 * CC * DKK + c * DKK);
        #pragma unroll
        for (int j = 0; j < 4; ++j) {
            float4 a = q4[j];
            aq[4*j+0] += xv * a.x; aq[4*j+1] += xv * a.y;
            aq[4*j+2] += xv * a.z; aq[4*j+3] += xv * a.w;
            float4 bk = k4[j];
            ak[4*j+0] += xv * bk.x; ak[4*j+1] += xv * bk.y;
            ak[4*j+2] += xv * bk.z; ak[4*j+3] += xv * bk.w;
            float4 cv = v4[j];
            av[4*j+0] += xv * cv.x; av[4*j+1] += xv * cv.y;
            av[4*j+2] += xv * cv.z; av[4*j+3] += xv * cv.w;
        }
    }
    // combine the 4 c-quarters (lanes stride 16)
    #pragma unroll
    for (int i = 0; i < DKK; ++i) {
        aq[i] += __shfl_xor(aq[i], 16); aq[i] += __shfl_xor(aq[i], 32);
        ak[i] += __shfl_xor(ak[i], 16); ak[i] += __shfl_xor(ak[i], 32);
        av[i] += __shfl_xor(av[i], 16); av[i] += __shfl_xor(av[i], 32);
    }

    float sq = 0.f, sk = 0.f;
    #pragma unroll
    for (int i = 0; i < DKK; ++i) { sq += aq[i]*aq[i]; sk += ak[i]*ak[i]; }
    const float rq = LOG2E / (sqrtf(sq) + EPSF);   // log2e folded into Q
    const float rk = 1.0f / (sqrtf(sk) + EPSF);

    if (cq == 0) {                                 // QP store
        __attribute__((aligned(16))) unsigned short qp[32];
        #pragma unroll
        for (int g = 0; g < 4; ++g)
            #pragma unroll
            for (int j = 0; j < 4; ++j) {
                const float qv = aq[g*4+j] * rq;
                unsigned short hq = f2bf(qv);
                qp[g*8+j]   = hq;
                qp[g*8+4+j] = f2bf(qv - bf2f(hq));
            }
        const size_t base = ((size_t)bh * NN + n) * 32;
        #pragma unroll
        for (int j = 0; j < 4; ++j)
            ((uint4*)(QP + base))[j] = ((const uint4*)qp)[j];
    } else if (cq == 1) {                          // KP store
        __attribute__((aligned(16))) unsigned short kp[32];
        #pragma unroll
        for (int g = 0; g < 4; ++g)
            #pragma unroll
            for (int j = 0; j < 4; ++j) {
                const float kv = ak[g*4+j] * rk;
                unsigned short hk = f2bf(kv);
                kp[g*8+j]   = hk;
                kp[g*8+4+j] = f2bf(kv - bf2f(hk));
            }
        const size_t base = ((size_t)bh * NN + n) * 32;
        #pragma unroll
        for (int j = 0; j < 4; ++j)
            ((uint4*)(KP + base))[j] = ((const uint4*)kp)[j];
    } else {
        // VP scatter: tile = n/16, g = (n%16)/4, slot = n%4; cq==2 -> hi, cq==3 -> lo
        const size_t vbase = (((size_t)bh * DKK) * 256 + (n >> 4)) * 32
                             + ((n >> 2) & 3) * 8 + (n & 3) + (cq == 2 ? 0 : 4);
        #pragma unroll
        for (int i = 0; i < DKK; ++i) {
            const float vv = av[i];
            const unsigned short hv = f2bf(vv);
            VP[vbase + (size_t)i * 256 * 32] =
                (cq == 2) ? hv : f2bf(vv - bf2f(hv));
        }
    }
}

// ---------------------------------------------------------------------------
// One 16-key tile of the attention inner loop (6 MFMA, 8 exp2).
// ---------------------------------------------------------------------------
__device__ __forceinline__ void attn_tile(
    const Frag& kc, const Frag& vc,
    const Frag& qahB, const Frag& qalB, const Frag& qbhB, const Frag& qblB,
    f4& oCa, f4& oCb, float& la, float& lb)
{
    const f4 zero = {0.f, 0.f, 0.f, 0.f};
    Frag kA2;                              // [K_hi | 0]
    kA2.p.lo = kc.p.lo; kA2.p.hi = make_uint2(0u, 0u);

    f4 sa = __builtin_amdgcn_mfma_f32_16x16x32_bf16(kA2.v, qalB.v, zero, 0, 0, 0);
    sa    = __builtin_amdgcn_mfma_f32_16x16x32_bf16(kc.v,  qahB.v, sa,   0, 0, 0);
    f4 sb = __builtin_amdgcn_mfma_f32_16x16x32_bf16(kA2.v, qblB.v, zero, 0, 0, 0);
    sb    = __builtin_amdgcn_mfma_f32_16x16x32_bf16(kc.v,  qbhB.v, sb,   0, 0, 0);

    const float pa0 = __builtin_amdgcn_exp2f(sa[0]), pa1 = __builtin_amdgcn_exp2f(sa[1]);
    const float pa2 = __builtin_amdgcn_exp2f(sa[2]), pa3 = __builtin_amdgcn_exp2f(sa[3]);
    const float pb0 = __builtin_amdgcn_exp2f(sb[0]), pb1 = __builtin_amdgcn_exp2f(sb[1]);
    const float pb2 = __builtin_amdgcn_exp2f(sb[2]), pb3 = __builtin_amdgcn_exp2f(sb[3]);
    la += (pa0 + pa1) + (pa2 + pa3);
    lb += (pb0 + pb1) + (pb2 + pb3);

    unsigned int ua0, ua1, ub0, ub1;
    asm("v_cvt_pk_bf16_f32 %0, %1, %2" : "=v"(ua0) : "v"(pa0), "v"(pa1));
    asm("v_cvt_pk_bf16_f32 %0, %1, %2" : "=v"(ua1) : "v"(pa2), "v"(pa3));
    asm("v_cvt_pk_bf16_f32 %0, %1, %2" : "=v"(ub0) : "v"(pb0), "v"(pb1));
    asm("v_cvt_pk_bf16_f32 %0, %1, %2" : "=v"(ub1) : "v"(pb2), "v"(pb3));
    Frag pBa, pBb;
    pBa.p.lo = make_uint2(ua0, ua1); pBa.p.hi = pBa.p.lo;
    pBb.p.lo = make_uint2(ub0, ub1); pBb.p.hi = pBb.p.lo;

    oCa = __builtin_amdgcn_mfma_f32_16x16x32_bf16(vc.v, pBa.v, oCa, 0, 0, 0);
    oCb = __builtin_amdgcn_mfma_f32_16x16x32_bf16(vc.v, pBb.v, oCb, 0, 0, 0);
}

// ---------------------------------------------------------------------------
// Stage 2 (fused): 1024 blocks x 8 waves. Block = 32 q-rows; wave = one key
// split (512 keys, 32 tiles). Per tile: one dwordx4 each for K and V, 6 MFMA.
// Last tile peeled (no OOB prefetch). Epilogue: LDS-reduce the 8 splits,
// normalize by l, write O2T directly (combine kernel eliminated).
// bh = blockIdx&7 -> one bh's K/V working set per XCD L2 (round-robin).
// ---------------------------------------------------------------------------
__global__ __launch_bounds__(512, 8) void attn_kernel(
    const unsigned short* __restrict__ QP, const unsigned short* __restrict__ KP,
    const unsigned short* __restrict__ VP, float* __restrict__ O2T)
{
    const int bh    = blockIdx.x & 7;
    const int qg    = blockIdx.x >> 3;          // 0..127, 32 q-rows each
    const int split = threadIdx.x >> 6;         // 0..7
    const int lane  = threadIdx.x & 63;
    const int qb    = qg * 2;                   // qblocks qb, qb+1
    const int g = lane >> 4;
    const int r = lane & 15;

    // Q frags: one 16B load each -> [hi(4) | lo(4)]
    const size_t qoff = ((size_t)bh * NN + qb * 16 + r) * 32 + g * 8;
    Frag qa, qbf;
    qa.q  = *(const uint4*)(QP + qoff);
    qbf.q = *(const uint4*)(QP + qoff + 16 * 32);
    Frag qahB, qalB, qbhB, qblB;
    qahB.p.lo = qa.p.lo;  qahB.p.hi = qa.p.lo;
    qalB.p.lo = qa.p.hi;  qalB.p.hi = qa.p.hi;
    qbhB.p.lo = qbf.p.lo; qbhB.p.hi = qbf.p.lo;
    qblB.p.lo = qbf.p.hi; qblB.p.hi = qbf.p.hi;

    const int key0 = split * (NN / KSPLIT);
    const unsigned short* kp_p = KP + ((size_t)bh * NN + key0 + r) * 32 + g * 8;
    const unsigned short* vp_p = VP + (((size_t)bh * DKK + r) * 256 + (key0 >> 4)) * 32 + g * 8;

    f4 oCa = {0.f,0.f,0.f,0.f}, oCb = {0.f,0.f,0.f,0.f};
    float la = 0.f, lb = 0.f;

    Frag kc, vc;
    kc.q = *(const uint4*)kp_p;
    vc.q = *(const uint4*)vp_p;

    for (int t = 0; t < TILES - 1; ++t) {       // prefetch tiles 1..31: valid
        Frag kn, vn;
        kn.q = *(const uint4*)(kp_p + 512);
        vn.q = *(const uint4*)(vp_p + 32);
        kp_p += 512; vp_p += 32;

        attn_tile(kc, vc, qahB, qalB, qbhB, qblB, oCa, oCb, la, lb);

        kc = kn; vc = vn;
    }
    attn_tile(kc, vc, qahB, qalB, qbhB, qblB, oCa, oCb, la, lb);  // last tile

    la += __shfl_xor(la, 16); la += __shfl_xor(la, 32);
    lb += __shfl_xor(lb, 16); lb += __shfl_xor(lb, 32);

    // ---- cross-split reduction in LDS ----
    __shared__ float sO[KSPLIT][2][DKK][16];    // 16 KB
    __shared__ float sL[KSPLIT][32];            // 1 KB
    #pragma unroll
    for (int i = 0; i < 4; ++i) {
        sO[split][0][g * 4 + i][r] = oCa[i];
        sO[split][1][g * 4 + i][r] = oCb[i];
    }
    if (g == 0) { sL[split][r] = la; sL[split][16 + r] = lb; }
    __syncthreads();

    // 512 threads -> one output element each
    const int q   = threadIdx.x & 15;
    const int qb2 = (threadIdx.x >> 4) & 1;
    const int dv  = threadIdx.x >> 5;           // 0..15
    float num = 0.f, den = 0.f;
    #pragma unroll
    for (int s = 0; s < KSPLIT; ++s) {
        num += sO[s][qb2][dv][q];
        den += sL[s][qb2 * 16 + q];
    }
    const int b = bh >> 2, h = bh & 3;
    O2T[((size_t)b * CC + h * DKK + dv) * NN + qg * 32 + qb2 * 16 + q] = num / den;
}

// ---------------------------------------------------------------------------
// Stage 4: y[b,c,n] = sum_{h,v} o[b,h,n,v] * wo[h,c,v] / 8
// c is block-uniform -> wo rows come through the scalar cache.
// ---------------------------------------------------------------------------
__global__ __launch_bounds__(256) void out_kernel(
    const float* __restrict__ O2T, const float* __restrict__ wo,
    float* __restrict__ y)
{
    const int idx = blockIdx.x * 256 + threadIdx.x;   // (b*CC + c)*NN + n
    const int n  = idx & (NN - 1);
    const int bc = idx >> 12;
    const int c  = bc & (CC - 1);
    const int b  = bc >> 6;

    const float* ob = O2T + (size_t)b * CC * NN + n;
    float acc = 0.f;
    #pragma unroll
    for (int h = 0; h < NHEADS; ++h) {
        const float* wrow = wo + ((size_t)h * CC + c) * DKK;
        #pragma unroll
        for (int v = 0; v < DKK; ++v)
            acc += ob[(size_t)(h * DKK + v) * NN] * wrow[v];
    }
    y[idx] = acc * 0.125f;
}

// ---------------------------------------------------------------------------
extern "C" void kernel_launch(void* const* d_in, const int* in_sizes, int n_in,
                              void* d_out, int out_size, void* d_ws, size_t ws_size,
                              hipStream_t stream)
{
    const float* x  = (const float*)d_in[0];
    const float* wq = (const float*)d_in[1];
    const float* wk = (const float*)d_in[2];
    const float* wv = (const float*)d_in[3];
    const float* wo = (const float*)d_in[4];
    float* y = (float*)d_out;

    const size_t QE = (size_t)NBH * NN * 32;            // 1M shorts per buffer
    const size_t PADE = 1024;                           // 2KB pad (unused, safety)
    unsigned short* QP = (unsigned short*)d_ws;
    unsigned short* KP = QP + QE;
    unsigned short* VP = KP + QE + PADE;
    float* O2T = (float*)(VP + QE + PADE);

    const size_t used_bytes = (3 * QE + 2 * PADE) * sizeof(unsigned short)
                              + (size_t)BB * CC * NN * sizeof(float);

    zerofill_kernel<<<2048, 256, 0, stream>>>((uint4*)d_ws,
                                              (unsigned int)(used_bytes / 16));
    proj_kernel<<<NBH * 64, 256, 0, stream>>>(x, wq, wk, wv, QP, KP, VP);
    attn_kernel<<<NBH * 128, 512, 0, stream>>>(QP, KP, VP, O2T);
    out_kernel<<<(BB * CC * NN) / 256, 256, 0, stream>>>(O2T, wo, y);
}

// Round 6
// 56.361 us; speedup vs baseline: 9.8667x; 1.3552x over previous
//
#include <hip/hip_runtime.h>
#include <math.h>

#define NHEADS 4
#define DKK 16
#define CC 64
#define BB 2
#define NN 4096
#define NBH 8
#define EPSF 1e-8f
#define KSPLIT 8
#define TILES 32          // (NN/KSPLIT)/16 key-tiles per wave
#define LOG2E 1.44269504088896340736f

typedef __attribute__((ext_vector_type(8))) short bf8;
typedef __attribute__((ext_vector_type(4))) float f4;

union Frag { bf8 v; struct { uint2 lo, hi; } p; uint4 q; };

__device__ __forceinline__ unsigned short f2bf(float f) {
    union { float f; unsigned int u; } v; v.f = f;
    unsigned int r = v.u + 0x7FFFu + ((v.u >> 16) & 1u);   // RNE
    return (unsigned short)(r >> 16);
}
__device__ __forceinline__ float bf2f(unsigned short h) {
    union { unsigned int u; float f; } v; v.u = ((unsigned int)h) << 16;
    return v.f;
}

// ---------------------------------------------------------------------------
// Stage 0: zero only the pad regions (the sole ws bytes not provably written
// before any read). All other buffers are fully written each call.
// ---------------------------------------------------------------------------
__global__ __launch_bounds__(256) void zerofill_kernel(uint4* __restrict__ p1,
                                                       uint4* __restrict__ p2,
                                                       unsigned int count16)
{
    const uint4 z = make_uint4(0u, 0u, 0u, 0u);
    for (unsigned int i = threadIdx.x; i < count16; i += 256) { p1[i] = z; p2[i] = z; }
}

// ---------------------------------------------------------------------------
// Stage 1: projections + normalize + hi/lo bf16 split, interleaved layouts.
// c-reduction split 4 ways across lane groups (cq = lane>>4), combined with
// __shfl_xor(16/32).
// QP/KP[bh][n][32]: [g*8+j]=hi[g*4+j], [g*8+4+j]=lo[g*4+j] (Q scaled log2e).
// VP[bh][dv(16)][tile(256)][32]: [g*8+j]=hi of key tile*16+g*4+j, +4 = lo.
// ---------------------------------------------------------------------------
__global__ __launch_bounds__(256) void proj_kernel(
    const float* __restrict__ x, const float* __restrict__ wq,
    const float* __restrict__ wk, const float* __restrict__ wv,
    unsigned short* __restrict__ QP, unsigned short* __restrict__ KP,
    unsigned short* __restrict__ VP)
{
    __shared__ float sW[3 * CC * DKK];
    const int bh = blockIdx.x >> 6;
    const int n0 = (blockIdx.x & 63) * 64;
    const int b  = bh >> 2;
    const int h  = bh & 3;

    const int hbase = h * CC * DKK;
    for (int i = threadIdx.x; i < CC * DKK; i += 256) {
        sW[i]                = wq[hbase + i] * 0.125f;
        sW[CC * DKK + i]     = wk[hbase + i] * 0.125f;
        sW[2 * CC * DKK + i] = wv[hbase + i] * 0.125f;
    }
    __syncthreads();

    const int lane = threadIdx.x & 63;
    const int wave = threadIdx.x >> 6;
    const int n  = n0 + wave * 16 + (lane & 15);
    const int cq = lane >> 4;                     // this lane's c-quarter

    float aq[DKK] = {}, ak[DKK] = {}, av[DKK] = {};
    const float* xb = x + (size_t)b * CC * NN + n;
    for (int cc = 0; cc < 16; ++cc) {
        const int c = cq * 16 + cc;
        const float xv = xb[(size_t)c * NN];
        const float4* q4 = (const float4*)(sW + c * DKK);
        const float4* k4 = (const float4*)(sW + CC * DKK + c * DKK);
        const float4* v4 = (const float4*)(sW + 2 * CC * DKK + c * DKK);
        #pragma unroll
        for (int j = 0; j < 4; ++j) {
            float4 a = q4[j];
            aq[4*j+0] += xv * a.x; aq[4*j+1] += xv * a.y;
            aq[4*j+2] += xv * a.z; aq[4*j+3] += xv * a.w;
            float4 bk = k4[j];
            ak[4*j+0] += xv * bk.x; ak[4*j+1] += xv * bk.y;
            ak[4*j+2] += xv * bk.z; ak[4*j+3] += xv * bk.w;
            float4 cv = v4[j];
            av[4*j+0] += xv * cv.x; av[4*j+1] += xv * cv.y;
            av[4*j+2] += xv * cv.z; av[4*j+3] += xv * cv.w;
        }
    }
    #pragma unroll
    for (int i = 0; i < DKK; ++i) {
        aq[i] += __shfl_xor(aq[i], 16); aq[i] += __shfl_xor(aq[i], 32);
        ak[i] += __shfl_xor(ak[i], 16); ak[i] += __shfl_xor(ak[i], 32);
        av[i] += __shfl_xor(av[i], 16); av[i] += __shfl_xor(av[i], 32);
    }

    float sq = 0.f, sk = 0.f;
    #pragma unroll
    for (int i = 0; i < DKK; ++i) { sq += aq[i]*aq[i]; sk += ak[i]*ak[i]; }
    const float rq = LOG2E / (sqrtf(sq) + EPSF);   // log2e folded into Q
    const float rk = 1.0f / (sqrtf(sk) + EPSF);

    if (cq == 0) {                                 // QP store
        __attribute__((aligned(16))) unsigned short qp[32];
        #pragma unroll
        for (int g = 0; g < 4; ++g)
            #pragma unroll
            for (int j = 0; j < 4; ++j) {
                const float qv = aq[g*4+j] * rq;
                unsigned short hq = f2bf(qv);
                qp[g*8+j]   = hq;
                qp[g*8+4+j] = f2bf(qv - bf2f(hq));
            }
        const size_t base = ((size_t)bh * NN + n) * 32;
        #pragma unroll
        for (int j = 0; j < 4; ++j)
            ((uint4*)(QP + base))[j] = ((const uint4*)qp)[j];
    } else if (cq == 1) {                          // KP store
        __attribute__((aligned(16))) unsigned short kp[32];
        #pragma unroll
        for (int g = 0; g < 4; ++g)
            #pragma unroll
            for (int j = 0; j < 4; ++j) {
                const float kv = ak[g*4+j] * rk;
                unsigned short hk = f2bf(kv);
                kp[g*8+j]   = hk;
                kp[g*8+4+j] = f2bf(kv - bf2f(hk));
            }
        const size_t base = ((size_t)bh * NN + n) * 32;
        #pragma unroll
        for (int j = 0; j < 4; ++j)
            ((uint4*)(KP + base))[j] = ((const uint4*)kp)[j];
    } else {
        // VP scatter: tile = n/16, g = (n%16)/4, slot = n%4; cq==2 hi, cq==3 lo
        const size_t vbase = (((size_t)bh * DKK) * 256 + (n >> 4)) * 32
                             + ((n >> 2) & 3) * 8 + (n & 3) + (cq == 2 ? 0 : 4);
        #pragma unroll
        for (int i = 0; i < DKK; ++i) {
            const float vv = av[i];
            const unsigned short hv = f2bf(vv);
            VP[vbase + (size_t)i * 256 * 32] =
                (cq == 2) ? hv : f2bf(vv - bf2f(hv));
        }
    }
}

// ---------------------------------------------------------------------------
// One 16-key tile x 4 q-frags (12 MFMA, 16 exp2). All frag indices are
// compile-time (unrolled) so everything stays in registers.
// ---------------------------------------------------------------------------
__device__ __forceinline__ void attn_tile(
    const Frag& kc, const Frag& vc,
    const Frag* qh_, const Frag* ql_, f4* oC, float* l_)
{
    const f4 zero = {0.f, 0.f, 0.f, 0.f};
    Frag kA2;                              // [K_hi | 0]
    kA2.p.lo = kc.p.lo; kA2.p.hi = make_uint2(0u, 0u);

    #pragma unroll
    for (int f = 0; f < 4; ++f) {
        f4 s = __builtin_amdgcn_mfma_f32_16x16x32_bf16(kA2.v, ql_[f].v, zero, 0, 0, 0);
        s    = __builtin_amdgcn_mfma_f32_16x16x32_bf16(kc.v,  qh_[f].v, s,    0, 0, 0);

        const float p0 = __builtin_amdgcn_exp2f(s[0]);
        const float p1 = __builtin_amdgcn_exp2f(s[1]);
        const float p2 = __builtin_amdgcn_exp2f(s[2]);
        const float p3 = __builtin_amdgcn_exp2f(s[3]);
        l_[f] += (p0 + p1) + (p2 + p3);

        unsigned int u0, u1;
        asm("v_cvt_pk_bf16_f32 %0, %1, %2" : "=v"(u0) : "v"(p0), "v"(p1));
        asm("v_cvt_pk_bf16_f32 %0, %1, %2" : "=v"(u1) : "v"(p2), "v"(p3));
        Frag pB;
        pB.p.lo = make_uint2(u0, u1); pB.p.hi = pB.p.lo;   // [P^T | P^T]

        oC[f] = __builtin_amdgcn_mfma_f32_16x16x32_bf16(vc.v, pB.v, oC[f], 0, 0, 0);
    }
}

// ---------------------------------------------------------------------------
// Stage 2 (fused): 512 blocks x 8 waves. Block = 64 q-rows; wave = one key
// split (512 keys, 32 tiles) x 4 q-frags -> each 2-load tile feeds 64 q-rows
// (2x the reuse of R5, half the VMEM instructions). Last tile peeled (no OOB).
// Epilogue: LDS-reduce 8 splits, normalize, write O2T.
// bh = blockIdx&7 -> one bh's K/V working set per XCD L2 (round-robin).
// ---------------------------------------------------------------------------
__global__ __launch_bounds__(512, 4) void attn_kernel(
    const unsigned short* __restrict__ QP, const unsigned short* __restrict__ KP,
    const unsigned short* __restrict__ VP, float* __restrict__ O2T)
{
    const int bh    = blockIdx.x & 7;
    const int qg    = blockIdx.x >> 3;          // 0..63, 64 q-rows each
    const int split = threadIdx.x >> 6;         // 0..7
    const int lane  = threadIdx.x & 63;
    const int g = lane >> 4;
    const int r = lane & 15;

    // 4 Q frags, each one 16B load -> [hi(4) | lo(4)], duplicated for MFMA B
    Frag qh_[4], ql_[4];
    #pragma unroll
    for (int f = 0; f < 4; ++f) {
        Frag qa;
        qa.q = *(const uint4*)(QP + ((size_t)bh * NN + qg * 64 + f * 16 + r) * 32 + g * 8);
        qh_[f].p.lo = qa.p.lo; qh_[f].p.hi = qa.p.lo;
        ql_[f].p.lo = qa.p.hi; ql_[f].p.hi = qa.p.hi;
    }

    const int key0 = split * (NN / KSPLIT);
    const unsigned short* kp_p = KP + ((size_t)bh * NN + key0 + r) * 32 + g * 8;
    const unsigned short* vp_p = VP + (((size_t)bh * DKK + r) * 256 + (key0 >> 4)) * 32 + g * 8;

    f4 oC[4] = {{0.f,0.f,0.f,0.f},{0.f,0.f,0.f,0.f},{0.f,0.f,0.f,0.f},{0.f,0.f,0.f,0.f}};
    float l_[4] = {0.f, 0.f, 0.f, 0.f};

    Frag kc, vc;
    kc.q = *(const uint4*)kp_p;
    vc.q = *(const uint4*)vp_p;

    for (int t = 0; t < TILES - 1; ++t) {       // prefetch tiles 1..31: valid
        Frag kn, vn;
        kn.q = *(const uint4*)(kp_p + 512);
        vn.q = *(const uint4*)(vp_p + 32);
        kp_p += 512; vp_p += 32;

        attn_tile(kc, vc, qh_, ql_, oC, l_);

        kc = kn; vc = vn;
    }
    attn_tile(kc, vc, qh_, ql_, oC, l_);        // last tile (peeled)

    #pragma unroll
    for (int f = 0; f < 4; ++f) {
        l_[f] += __shfl_xor(l_[f], 16);
        l_[f] += __shfl_xor(l_[f], 32);
    }

    // ---- cross-split reduction in LDS ----
    __shared__ float sO[KSPLIT][4][DKK][17];    // ~34.8 KB, padded (<=2-way)
    __shared__ float sL[KSPLIT][4][17];         // ~2.2 KB
    #pragma unroll
    for (int f = 0; f < 4; ++f)
        #pragma unroll
        for (int i = 0; i < 4; ++i)
            sO[split][f][g * 4 + i][r] = oC[f][i];
    if (g == 0) {
        #pragma unroll
        for (int f = 0; f < 4; ++f) sL[split][f][r] = l_[f];
    }
    __syncthreads();

    // 512 threads: each handles (qq, dv0) and (qq, dv0+8)
    const int qq  = threadIdx.x & 63;
    const int f   = qq >> 4;
    const int rr  = qq & 15;
    const int dv0 = threadIdx.x >> 6;           // 0..7
    const int b = bh >> 2, h = bh & 3;

    float den = 0.f;
    #pragma unroll
    for (int s = 0; s < KSPLIT; ++s) den += sL[s][f][rr];
    const float rd = 1.0f / den;

    #pragma unroll
    for (int dd = 0; dd < 2; ++dd) {
        const int dv = dv0 + dd * 8;
        float num = 0.f;
        #pragma unroll
        for (int s = 0; s < KSPLIT; ++s) num += sO[s][f][dv][rr];
        O2T[((size_t)b * CC + h * DKK + dv) * NN + qg * 64 + qq] = num * rd;
    }
}

// ---------------------------------------------------------------------------
// Stage 4: y[b,c,n] = sum_{h,v} o[b,h,n,v] * wo[h,c,v] / 8.
// 4 c-outputs per thread -> O2T re-read traffic /4; wo reads are block-uniform
// (scalar cache).
// ---------------------------------------------------------------------------
__global__ __launch_bounds__(256) void out_kernel(
    const float* __restrict__ O2T, const float* __restrict__ wo,
    float* __restrict__ y)
{
    const int idx = blockIdx.x * 256 + threadIdx.x;   // (b*16 + cg)*NN + n
    const int n   = idx & (NN - 1);
    const int bcg = idx >> 12;
    const int cg  = bcg & 15;                         // c-group of 4
    const int b   = bcg >> 4;

    const float* ob = O2T + (size_t)b * CC * NN + n;
    float acc[4] = {0.f, 0.f, 0.f, 0.f};
    #pragma unroll
    for (int h = 0; h < NHEADS; ++h)
        #pragma unroll
        for (int v = 0; v < DKK; ++v) {
            const float o = ob[(size_t)(h * DKK + v) * NN];
            #pragma unroll
            for (int c2 = 0; c2 < 4; ++c2)
                acc[c2] += o * wo[((size_t)h * CC + cg * 4 + c2) * DKK + v];
        }
    #pragma unroll
    for (int c2 = 0; c2 < 4; ++c2)
        y[((size_t)b * CC + cg * 4 + c2) * NN + n] = acc[c2] * 0.125f;
}

// ---------------------------------------------------------------------------
extern "C" void kernel_launch(void* const* d_in, const int* in_sizes, int n_in,
                              void* d_out, int out_size, void* d_ws, size_t ws_size,
                              hipStream_t stream)
{
    const float* x  = (const float*)d_in[0];
    const float* wq = (const float*)d_in[1];
    const float* wk = (const float*)d_in[2];
    const float* wv = (const float*)d_in[3];
    const float* wo = (const float*)d_in[4];
    float* y = (float*)d_out;

    const size_t QE = (size_t)NBH * NN * 32;            // 1M shorts per buffer
    const size_t PADE = 1024;                           // 2KB pad (safety)
    unsigned short* QP = (unsigned short*)d_ws;
    unsigned short* KP = QP + QE;
    unsigned short* VP = KP + QE + PADE;
    float* O2T = (float*)(VP + QE + PADE);

    zerofill_kernel<<<1, 256, 0, stream>>>((uint4*)(KP + QE), (uint4*)(VP + QE),
                                           (unsigned int)(PADE * 2 / 16));
    proj_kernel<<<NBH * 64, 256, 0, stream>>>(x, wq, wk, wv, QP, KP, VP);
    attn_kernel<<<NBH * 64, 512, 0, stream>>>(QP, KP, VP, O2T);
    out_kernel<<<(BB * 16 * NN) / 256, 256, 0, stream>>>(O2T, wo, y);
}

// Round 7
// 45.496 us; speedup vs baseline: 12.2229x; 1.2388x over previous
//
#include <hip/hip_runtime.h>
#include <math.h>

#define NHEADS 4
#define DKK 16
#define CC 64
#define BB 2
#define NN 4096
#define NBH 8
#define EPSF 1e-8f
#define KSPLIT 8
#define TILES 32          // (NN/KSPLIT)/16 key-tiles per wave
#define LOG2E 1.44269504088896340736f

typedef __attribute__((ext_vector_type(8))) short bf8;
typedef __attribute__((ext_vector_type(4))) float f4;

union Frag { bf8 v; struct { uint2 lo, hi; } p; uint4 q; };

__device__ __forceinline__ unsigned short f2bf(float f) {
    union { float f; unsigned int u; } v; v.f = f;
    unsigned int r = v.u + 0x7FFFu + ((v.u >> 16) & 1u);   // RNE
    return (unsigned short)(r >> 16);
}
__device__ __forceinline__ float bf2f(unsigned short h) {
    union { unsigned int u; float f; } v; v.u = ((unsigned int)h) << 16;
    return v.f;
}

// ---------------------------------------------------------------------------
// Stage 1: projections + normalize + bf16 convert, MFMA-ready layouts.
// Q/K are stored hi-only (error budget: S lo-correction is 6x below the
// already-accepted P-rounding error). V keeps hi+lo (free in the PV MFMA).
// QP/KP[bh][n][16] bf16 (Q scaled by log2e).
// VP[bh][dv(16)][tile(256)][32]: [g*8+j]=hi of key tile*16+g*4+j, +4 = lo.
// c-reduction split 4 ways across lane groups, combined via __shfl_xor.
// ---------------------------------------------------------------------------
__global__ __launch_bounds__(256) void proj_kernel(
    const float* __restrict__ x, const float* __restrict__ wq,
    const float* __restrict__ wk, const float* __restrict__ wv,
    unsigned short* __restrict__ QP, unsigned short* __restrict__ KP,
    unsigned short* __restrict__ VP)
{
    __shared__ float sW[3 * CC * DKK];
    const int bh = blockIdx.x >> 6;
    const int n0 = (blockIdx.x & 63) * 64;
    const int b  = bh >> 2;
    const int h  = bh & 3;

    const int hbase = h * CC * DKK;
    for (int i = threadIdx.x; i < CC * DKK; i += 256) {
        sW[i]                = wq[hbase + i] * 0.125f;
        sW[CC * DKK + i]     = wk[hbase + i] * 0.125f;
        sW[2 * CC * DKK + i] = wv[hbase + i] * 0.125f;
    }
    __syncthreads();

    const int lane = threadIdx.x & 63;
    const int wave = threadIdx.x >> 6;
    const int n  = n0 + wave * 16 + (lane & 15);
    const int cq = lane >> 4;                     // this lane's c-quarter

    float aq[DKK] = {}, ak[DKK] = {}, av[DKK] = {};
    const float* xb = x + (size_t)b * CC * NN + n;
    for (int cc = 0; cc < 16; ++cc) {
        const int c = cq * 16 + cc;
        const float xv = xb[(size_t)c * NN];
        const float4* q4 = (const float4*)(sW + c * DKK);
        const float4* k4 = (const float4*)(sW + CC * DKK + c * DKK);
        const float4* v4 = (const float4*)(sW + 2 * CC * DKK + c * DKK);
        #pragma unroll
        for (int j = 0; j < 4; ++j) {
            float4 a = q4[j];
            aq[4*j+0] += xv * a.x; aq[4*j+1] += xv * a.y;
            aq[4*j+2] += xv * a.z; aq[4*j+3] += xv * a.w;
            float4 bk = k4[j];
            ak[4*j+0] += xv * bk.x; ak[4*j+1] += xv * bk.y;
            ak[4*j+2] += xv * bk.z; ak[4*j+3] += xv * bk.w;
            float4 cv = v4[j];
            av[4*j+0] += xv * cv.x; av[4*j+1] += xv * cv.y;
            av[4*j+2] += xv * cv.z; av[4*j+3] += xv * cv.w;
        }
    }
    #pragma unroll
    for (int i = 0; i < DKK; ++i) {
        aq[i] += __shfl_xor(aq[i], 16); aq[i] += __shfl_xor(aq[i], 32);
        ak[i] += __shfl_xor(ak[i], 16); ak[i] += __shfl_xor(ak[i], 32);
        av[i] += __shfl_xor(av[i], 16); av[i] += __shfl_xor(av[i], 32);
    }

    float sq = 0.f, sk = 0.f;
    #pragma unroll
    for (int i = 0; i < DKK; ++i) { sq += aq[i]*aq[i]; sk += ak[i]*ak[i]; }
    const float rq = LOG2E / (sqrtf(sq) + EPSF);   // log2e folded into Q
    const float rk = 1.0f / (sqrtf(sk) + EPSF);

    if (cq == 0) {                                 // QP store (hi-only)
        __attribute__((aligned(16))) unsigned short qp[16];
        #pragma unroll
        for (int i = 0; i < DKK; ++i) qp[i] = f2bf(aq[i] * rq);
        const size_t base = ((size_t)bh * NN + n) * 16;
        ((uint4*)(QP + base))[0] = ((const uint4*)qp)[0];
        ((uint4*)(QP + base))[1] = ((const uint4*)qp)[1];
    } else if (cq == 1) {                          // KP store (hi-only)
        __attribute__((aligned(16))) unsigned short kp[16];
        #pragma unroll
        for (int i = 0; i < DKK; ++i) kp[i] = f2bf(ak[i] * rk);
        const size_t base = ((size_t)bh * NN + n) * 16;
        ((uint4*)(KP + base))[0] = ((const uint4*)kp)[0];
        ((uint4*)(KP + base))[1] = ((const uint4*)kp)[1];
    } else {
        // VP scatter: tile = n/16, g = (n%16)/4, slot = n%4; cq==2 hi, cq==3 lo
        const size_t vbase = (((size_t)bh * DKK) * 256 + (n >> 4)) * 32
                             + ((n >> 2) & 3) * 8 + (n & 3) + (cq == 2 ? 0 : 4);
        #pragma unroll
        for (int i = 0; i < DKK; ++i) {
            const float vv = av[i];
            const unsigned short hv = f2bf(vv);
            VP[vbase + (size_t)i * 256 * 32] =
                (cq == 2) ? hv : f2bf(vv - bf2f(hv));
        }
    }
}

// ---------------------------------------------------------------------------
// One 16-key tile x 4 q-frags (8 MFMA, 16 exp2). All indices compile-time.
// ---------------------------------------------------------------------------
__device__ __forceinline__ void attn_tile(
    const uint2 khi, const Frag& vc,
    const Frag* qh_, f4* oC, float* l_)
{
    const f4 zero = {0.f, 0.f, 0.f, 0.f};
    Frag kA;                               // [K_hi | 0]
    kA.p.lo = khi; kA.p.hi = make_uint2(0u, 0u);

    #pragma unroll
    for (int f = 0; f < 4; ++f) {
        f4 s = __builtin_amdgcn_mfma_f32_16x16x32_bf16(kA.v, qh_[f].v, zero, 0, 0, 0);

        const float p0 = __builtin_amdgcn_exp2f(s[0]);
        const float p1 = __builtin_amdgcn_exp2f(s[1]);
        const float p2 = __builtin_amdgcn_exp2f(s[2]);
        const float p3 = __builtin_amdgcn_exp2f(s[3]);
        l_[f] += (p0 + p1) + (p2 + p3);

        unsigned int u0, u1;
        asm("v_cvt_pk_bf16_f32 %0, %1, %2" : "=v"(u0) : "v"(p0), "v"(p1));
        asm("v_cvt_pk_bf16_f32 %0, %1, %2" : "=v"(u1) : "v"(p2), "v"(p3));
        Frag pB;
        pB.p.lo = make_uint2(u0, u1); pB.p.hi = pB.p.lo;   // [P^T | P^T]

        oC[f] = __builtin_amdgcn_mfma_f32_16x16x32_bf16(vc.v, pB.v, oC[f], 0, 0, 0);
    }
}

// ---------------------------------------------------------------------------
// Stage 2 (fused): 512 blocks x 8 waves. Block = 64 q-rows; wave = one key
// split (512 keys, 32 tiles) x 4 q-frags. Per tile: 8B K-load + 16B V-load,
// 8 MFMA, 16 exp2. Prefetch depth 2, unroll-2, last two tiles peeled (no OOB
// read anywhere -> ws is replay-deterministic without zerofill).
// Epilogue: LDS-reduce 8 splits, normalize, write O2T.
// bh = blockIdx&7 -> one bh's K/V working set per XCD L2 (round-robin).
// ---------------------------------------------------------------------------
__global__ __launch_bounds__(512, 4) void attn_kernel(
    const unsigned short* __restrict__ QP, const unsigned short* __restrict__ KP,
    const unsigned short* __restrict__ VP, float* __restrict__ O2T)
{
    const int bh    = blockIdx.x & 7;
    const int qg    = blockIdx.x >> 3;          // 0..63, 64 q-rows each
    const int split = threadIdx.x >> 6;         // 0..7
    const int lane  = threadIdx.x & 63;
    const int g = lane >> 4;
    const int r = lane & 15;

    // 4 Q frags (hi-only), each an 8B load duplicated into both B halves
    Frag qh_[4];
    #pragma unroll
    for (int f = 0; f < 4; ++f) {
        const uint2 qv = *(const uint2*)(QP + ((size_t)bh * NN + qg * 64 + f * 16 + r) * 16 + g * 4);
        qh_[f].p.lo = qv; qh_[f].p.hi = qv;
    }

    const int key0 = split * (NN / KSPLIT);
    const unsigned short* kp_p = KP + ((size_t)bh * NN + key0 + r) * 16 + g * 4;
    const unsigned short* vp_p = VP + (((size_t)bh * DKK + r) * 256 + (key0 >> 4)) * 32 + g * 8;

    f4 oC[4] = {{0.f,0.f,0.f,0.f},{0.f,0.f,0.f,0.f},{0.f,0.f,0.f,0.f},{0.f,0.f,0.f,0.f}};
    float l_[4] = {0.f, 0.f, 0.f, 0.f};

    // prefetch depth 2 (tiles 0 and 1), unroll-2 main loop
    uint2 k0 = *(const uint2*)kp_p;
    Frag  v0; v0.q = *(const uint4*)vp_p;
    uint2 k1 = *(const uint2*)(kp_p + 256);
    Frag  v1; v1.q = *(const uint4*)(vp_p + 32);
    kp_p += 512; vp_p += 64;                    // -> tile t+2

    for (int t = 0; t < TILES - 2; t += 2) {    // 15 iters; max prefetch = 31
        const uint2 kn0 = *(const uint2*)kp_p;
        Frag vn0; vn0.q = *(const uint4*)vp_p;
        attn_tile(k0, v0, qh_, oC, l_);
        const uint2 kn1 = *(const uint2*)(kp_p + 256);
        Frag vn1; vn1.q = *(const uint4*)(vp_p + 32);
        attn_tile(k1, v1, qh_, oC, l_);
        k0 = kn0; v0 = vn0; k1 = kn1; v1 = vn1;
        kp_p += 512; vp_p += 64;
    }
    attn_tile(k0, v0, qh_, oC, l_);             // tile 30
    attn_tile(k1, v1, qh_, oC, l_);             // tile 31

    #pragma unroll
    for (int f = 0; f < 4; ++f) {
        l_[f] += __shfl_xor(l_[f], 16);
        l_[f] += __shfl_xor(l_[f], 32);
    }

    // ---- cross-split reduction in LDS ----
    __shared__ float sO[KSPLIT][4][DKK][17];    // ~34.8 KB, padded (<=2-way)
    __shared__ float sL[KSPLIT][4][17];         // ~2.2 KB
    #pragma unroll
    for (int f = 0; f < 4; ++f)
        #pragma unroll
        for (int i = 0; i < 4; ++i)
            sO[split][f][g * 4 + i][r] = oC[f][i];
    if (g == 0) {
        #pragma unroll
        for (int f = 0; f < 4; ++f) sL[split][f][r] = l_[f];
    }
    __syncthreads();

    // 512 threads: each handles (qq, dv0) and (qq, dv0+8)
    const int qq  = threadIdx.x & 63;
    const int f   = qq >> 4;
    const int rr  = qq & 15;
    const int dv0 = threadIdx.x >> 6;           // 0..7
    const int b = bh >> 2, h = bh & 3;

    float den = 0.f;
    #pragma unroll
    for (int s = 0; s < KSPLIT; ++s) den += sL[s][f][rr];
    const float rd = 1.0f / den;

    #pragma unroll
    for (int dd = 0; dd < 2; ++dd) {
        const int dv = dv0 + dd * 8;
        float num = 0.f;
        #pragma unroll
        for (int s = 0; s < KSPLIT; ++s) num += sO[s][f][dv][rr];
        O2T[((size_t)b * CC + h * DKK + dv) * NN + qg * 64 + qq] = num * rd;
    }
}

// ---------------------------------------------------------------------------
// Stage 3: y[b,c,n] = sum_{h,v} o[b,h,n,v] * wo[h,c,v] / 8.
// 4 c-outputs per thread; wo reads are block-uniform (scalar cache).
// ---------------------------------------------------------------------------
__global__ __launch_bounds__(256) void out_kernel(
    const float* __restrict__ O2T, const float* __restrict__ wo,
    float* __restrict__ y)
{
    const int idx = blockIdx.x * 256 + threadIdx.x;   // (b*16 + cg)*NN + n
    const int n   = idx & (NN - 1);
    const int bcg = idx >> 12;
    const int cg  = bcg & 15;                         // c-group of 4
    const int b   = bcg >> 4;

    const float* ob = O2T + (size_t)b * CC * NN + n;
    float acc[4] = {0.f, 0.f, 0.f, 0.f};
    #pragma unroll
    for (int h = 0; h < NHEADS; ++h)
        #pragma unroll
        for (int v = 0; v < DKK; ++v) {
            const float o = ob[(size_t)(h * DKK + v) * NN];
            #pragma unroll
            for (int c2 = 0; c2 < 4; ++c2)
                acc[c2] += o * wo[((size_t)h * CC + cg * 4 + c2) * DKK + v];
        }
    #pragma unroll
    for (int c2 = 0; c2 < 4; ++c2)
        y[((size_t)b * CC + cg * 4 + c2) * NN + n] = acc[c2] * 0.125f;
}

// ---------------------------------------------------------------------------
extern "C" void kernel_launch(void* const* d_in, const int* in_sizes, int n_in,
                              void* d_out, int out_size, void* d_ws, size_t ws_size,
                              hipStream_t stream)
{
    const float* x  = (const float*)d_in[0];
    const float* wq = (const float*)d_in[1];
    const float* wk = (const float*)d_in[2];
    const float* wv = (const float*)d_in[3];
    const float* wo = (const float*)d_in[4];
    float* y = (float*)d_out;

    const size_t QKE = (size_t)NBH * NN * 16;           // QP/KP: 512K shorts
    const size_t VE  = (size_t)NBH * NN * 32;           // VP: 1M shorts
    unsigned short* QP = (unsigned short*)d_ws;
    unsigned short* KP = QP + QKE;
    unsigned short* VP = KP + QKE;
    float* O2T = (float*)(VP + VE);

    proj_kernel<<<NBH * 64, 256, 0, stream>>>(x, wq, wk, wv, QP, KP, VP);
    attn_kernel<<<NBH * 64, 512, 0, stream>>>(QP, KP, VP, O2T);
    out_kernel<<<(BB * 16 * NN) / 256, 256, 0, stream>>>(O2T, wo, y);
}

// Round 9
// 42.294 us; speedup vs baseline: 13.1483x; 1.0757x over previous
//
#include <hip/hip_runtime.h>
#include <math.h>

#define NHEADS 4
#define DKK 16
#define CC 64
#define BB 2
#define NN 4096
#define NBH 8
#define EPSF 1e-8f
#define KSPLIT 8
#define TPAIRS 16         // 32-key tile-pairs per wave (512 keys per split)
#define LOG2E 1.44269504088896340736f

typedef __attribute__((ext_vector_type(8))) short bf8;
typedef __attribute__((ext_vector_type(4))) float f4;

union Frag { bf8 v; struct { uint2 lo, hi; } p; uint4 q; };

__device__ __forceinline__ unsigned short f2bf(float f) {
    union { float f; unsigned int u; } v; v.f = f;
    unsigned int r = v.u + 0x7FFFu + ((v.u >> 16) & 1u);   // RNE
    return (unsigned short)(r >> 16);
}

// ---------------------------------------------------------------------------
// Stage 1: projections + normalize + bf16 convert, MFMA-ready layouts.
// QP/KP[bh][n][16] bf16 hi-only (Q scaled by log2e).
// VP hi-only, pair-interleaved: VP[bh][dv(16)][pt(128)][32],
//   slot = ((n>>2)&3)*8 + ((n>>4)&1)*4 + (n&3)  (even tile -> j0..3, odd -> j4..7)
// c-reduction split 4 ways across lane groups, combined via __shfl_xor.
// ---------------------------------------------------------------------------
__global__ __launch_bounds__(256) void proj_kernel(
    const float* __restrict__ x, const float* __restrict__ wq,
    const float* __restrict__ wk, const float* __restrict__ wv,
    unsigned short* __restrict__ QP, unsigned short* __restrict__ KP,
    unsigned short* __restrict__ VP)
{
    __shared__ float sW[3 * CC * DKK];
    const int bh = blockIdx.x >> 6;
    const int n0 = (blockIdx.x & 63) * 64;
    const int b  = bh >> 2;
    const int h  = bh & 3;

    const int hbase = h * CC * DKK;
    for (int i = threadIdx.x; i < CC * DKK; i += 256) {
        sW[i]                = wq[hbase + i] * 0.125f;
        sW[CC * DKK + i]     = wk[hbase + i] * 0.125f;
        sW[2 * CC * DKK + i] = wv[hbase + i] * 0.125f;
    }
    __syncthreads();

    const int lane = threadIdx.x & 63;
    const int wave = threadIdx.x >> 6;
    const int n  = n0 + wave * 16 + (lane & 15);
    const int cq = lane >> 4;                     // this lane's c-quarter

    float aq[DKK] = {}, ak[DKK] = {}, av[DKK] = {};
    const float* xb = x + (size_t)b * CC * NN + n;
    for (int cc = 0; cc < 16; ++cc) {
        const int c = cq * 16 + cc;
        const float xv = xb[(size_t)c * NN];
        const float4* q4 = (const float4*)(sW + c * DKK);
        const float4* k4 = (const float4*)(sW + CC * DKK + c * DKK);
        const float4* v4 = (const float4*)(sW + 2 * CC * DKK + c * DKK);
        #pragma unroll
        for (int j = 0; j < 4; ++j) {
            float4 a = q4[j];
            aq[4*j+0] += xv * a.x; aq[4*j+1] += xv * a.y;
            aq[4*j+2] += xv * a.z; aq[4*j+3] += xv * a.w;
            float4 bk = k4[j];
            ak[4*j+0] += xv * bk.x; ak[4*j+1] += xv * bk.y;
            ak[4*j+2] += xv * bk.z; ak[4*j+3] += xv * bk.w;
            float4 cv = v4[j];
            av[4*j+0] += xv * cv.x; av[4*j+1] += xv * cv.y;
            av[4*j+2] += xv * cv.z; av[4*j+3] += xv * cv.w;
        }
    }
    #pragma unroll
    for (int i = 0; i < DKK; ++i) {
        aq[i] += __shfl_xor(aq[i], 16); aq[i] += __shfl_xor(aq[i], 32);
        ak[i] += __shfl_xor(ak[i], 16); ak[i] += __shfl_xor(ak[i], 32);
        av[i] += __shfl_xor(av[i], 16); av[i] += __shfl_xor(av[i], 32);
    }

    float sq = 0.f, sk = 0.f;
    #pragma unroll
    for (int i = 0; i < DKK; ++i) { sq += aq[i]*aq[i]; sk += ak[i]*ak[i]; }
    const float rq = LOG2E / (sqrtf(sq) + EPSF);   // log2e folded into Q
    const float rk = 1.0f / (sqrtf(sk) + EPSF);

    if (cq == 0) {                                 // QP store (hi-only)
        __attribute__((aligned(16))) unsigned short qp[16];
        #pragma unroll
        for (int i = 0; i < DKK; ++i) qp[i] = f2bf(aq[i] * rq);
        const size_t base = ((size_t)bh * NN + n) * 16;
        ((uint4*)(QP + base))[0] = ((const uint4*)qp)[0];
        ((uint4*)(QP + base))[1] = ((const uint4*)qp)[1];
    } else if (cq == 1) {                          // KP store (hi-only)
        __attribute__((aligned(16))) unsigned short kp[16];
        #pragma unroll
        for (int i = 0; i < DKK; ++i) kp[i] = f2bf(ak[i] * rk);
        const size_t base = ((size_t)bh * NN + n) * 16;
        ((uint4*)(KP + base))[0] = ((const uint4*)kp)[0];
        ((uint4*)(KP + base))[1] = ((const uint4*)kp)[1];
    } else {
        // VP scatter (hi-only): cq==2 -> dv 0..7, cq==3 -> dv 8..15
        const int vslot = ((n >> 2) & 3) * 8 + ((n >> 4) & 1) * 4 + (n & 3);
        const int dv0 = (cq == 2) ? 0 : 8;
        #pragma unroll
        for (int i = 0; i < 8; ++i) {
            const int dv = dv0 + i;
            VP[(((size_t)bh * DKK + dv) * 128 + (n >> 5)) * 32 + vslot] = f2bf(av[dv]);
        }
    }
}

// ---------------------------------------------------------------------------
// One 32-key tile-pair x 4 q-frags: 12 MFMA (8 S + 4 PV), 32 exp2.
// PV packs both 16-key tiles into one MFMA (A=[V_e|V_o], B=[P_e|P_o]);
// l accumulated on the VALU (8 adds per frag) + post-loop shfl reduce
// (R7's proven mechanism; R8's ones-MFMA l was the NaN bisect suspect).
// ---------------------------------------------------------------------------
__device__ __forceinline__ void attn_pair(
    const uint2 ke, const uint2 ko, const Frag& vc,
    const Frag* qh_, f4* oC, float* l_)
{
    const f4 zero = {0.f, 0.f, 0.f, 0.f};
    Frag kAe, kAo;
    kAe.p.lo = ke; kAe.p.hi = make_uint2(0u, 0u);
    kAo.p.lo = ko; kAo.p.hi = make_uint2(0u, 0u);

    #pragma unroll
    for (int f = 0; f < 4; ++f) {
        f4 se = __builtin_amdgcn_mfma_f32_16x16x32_bf16(kAe.v, qh_[f].v, zero, 0, 0, 0);
        f4 so = __builtin_amdgcn_mfma_f32_16x16x32_bf16(kAo.v, qh_[f].v, zero, 0, 0, 0);

        const float pe0 = __builtin_amdgcn_exp2f(se[0]);
        const float pe1 = __builtin_amdgcn_exp2f(se[1]);
        const float pe2 = __builtin_amdgcn_exp2f(se[2]);
        const float pe3 = __builtin_amdgcn_exp2f(se[3]);
        const float po0 = __builtin_amdgcn_exp2f(so[0]);
        const float po1 = __builtin_amdgcn_exp2f(so[1]);
        const float po2 = __builtin_amdgcn_exp2f(so[2]);
        const float po3 = __builtin_amdgcn_exp2f(so[3]);

        l_[f] += ((pe0 + pe1) + (pe2 + pe3)) + ((po0 + po1) + (po2 + po3));

        unsigned int u0, u1, u2, u3;
        asm("v_cvt_pk_bf16_f32 %0, %1, %2" : "=v"(u0) : "v"(pe0), "v"(pe1));
        asm("v_cvt_pk_bf16_f32 %0, %1, %2" : "=v"(u1) : "v"(pe2), "v"(pe3));
        asm("v_cvt_pk_bf16_f32 %0, %1, %2" : "=v"(u2) : "v"(po0), "v"(po1));
        asm("v_cvt_pk_bf16_f32 %0, %1, %2" : "=v"(u3) : "v"(po2), "v"(po3));
        Frag pB;
        pB.p.lo = make_uint2(u0, u1);   // even tile -> positions j0..3
        pB.p.hi = make_uint2(u2, u3);   // odd tile  -> positions j4..7

        oC[f] = __builtin_amdgcn_mfma_f32_16x16x32_bf16(vc.v, pB.v, oC[f], 0, 0, 0);
    }
}

// ---------------------------------------------------------------------------
// Stage 2 (fused): 512 blocks x 8 waves. Block = 64 q-rows; wave = one key
// split (512 keys = 16 pairs) x 4 q-frags. Per pair: 2x8B K + 1x16B V loads,
// 12 MFMA, 32 exp2. Prefetch depth 2 pairs, unroll-2, last two pairs peeled
// (no OOB read anywhere -> replay-deterministic).
// Epilogue: LDS-reduce 8 splits, normalize, write O2T.
// ---------------------------------------------------------------------------
__global__ __launch_bounds__(512, 4) void attn_kernel(
    const unsigned short* __restrict__ QP, const unsigned short* __restrict__ KP,
    const unsigned short* __restrict__ VP, float* __restrict__ O2T)
{
    const int bh    = blockIdx.x & 7;
    const int qg    = blockIdx.x >> 3;          // 0..63, 64 q-rows each
    const int split = threadIdx.x >> 6;         // 0..7
    const int lane  = threadIdx.x & 63;
    const int g = lane >> 4;
    const int r = lane & 15;

    // 4 Q frags (hi-only), each an 8B load duplicated into both B halves
    Frag qh_[4];
    #pragma unroll
    for (int f = 0; f < 4; ++f) {
        const uint2 qv = *(const uint2*)(QP + ((size_t)bh * NN + qg * 64 + f * 16 + r) * 16 + g * 4);
        qh_[f].p.lo = qv; qh_[f].p.hi = qv;
    }

    const int key0 = split * (NN / KSPLIT);
    const unsigned short* kp_p = KP + ((size_t)bh * NN + key0 + r) * 16 + g * 4;
    const unsigned short* vp_p = VP + (((size_t)bh * DKK + r) * 128 + (key0 >> 5)) * 32 + g * 8;

    f4 oC[4] = {{0.f,0.f,0.f,0.f},{0.f,0.f,0.f,0.f},{0.f,0.f,0.f,0.f},{0.f,0.f,0.f,0.f}};
    float l_[4] = {0.f, 0.f, 0.f, 0.f};

    // prefetch depth 2 pairs (pairs 0 and 1), unroll-2 main loop
    uint2 ke0 = *(const uint2*)kp_p;
    uint2 ko0 = *(const uint2*)(kp_p + 256);
    Frag  v0; v0.q = *(const uint4*)vp_p;
    uint2 ke1 = *(const uint2*)(kp_p + 512);
    uint2 ko1 = *(const uint2*)(kp_p + 768);
    Frag  v1; v1.q = *(const uint4*)(vp_p + 32);
    kp_p += 1024; vp_p += 64;                   // -> pair t+2

    for (int t = 0; t < TPAIRS - 2; t += 2) {   // 7 iters; max prefetch pair 15
        const uint2 kne0 = *(const uint2*)kp_p;
        const uint2 kno0 = *(const uint2*)(kp_p + 256);
        Frag vn0; vn0.q = *(const uint4*)vp_p;
        attn_pair(ke0, ko0, v0, qh_, oC, l_);
        const uint2 kne1 = *(const uint2*)(kp_p + 512);
        const uint2 kno1 = *(const uint2*)(kp_p + 768);
        Frag vn1; vn1.q = *(const uint4*)(vp_p + 32);
        attn_pair(ke1, ko1, v1, qh_, oC, l_);
        ke0 = kne0; ko0 = kno0; v0 = vn0;
        ke1 = kne1; ko1 = kno1; v1 = vn1;
        kp_p += 1024; vp_p += 64;
    }
    attn_pair(ke0, ko0, v0, qh_, oC, l_);       // pair 14
    attn_pair(ke1, ko1, v1, qh_, oC, l_);       // pair 15

    // per-lane l_ covers this lane's 8 key-positions per pair; reduce the
    // 4 lane-groups (stride-16 lanes) -> full split-l in every lane
    #pragma unroll
    for (int f = 0; f < 4; ++f) {
        l_[f] += __shfl_xor(l_[f], 16);
        l_[f] += __shfl_xor(l_[f], 32);
    }

    // ---- cross-split reduction in LDS ----
    __shared__ float sO[KSPLIT][4][DKK][17];    // ~34.8 KB, padded (<=2-way)
    __shared__ float sL[KSPLIT][4][17];         // ~2.2 KB
    #pragma unroll
    for (int f = 0; f < 4; ++f)
        #pragma unroll
        for (int i = 0; i < 4; ++i)
            sO[split][f][g * 4 + i][r] = oC[f][i];
    if (g == 0) {
        #pragma unroll
        for (int f = 0; f < 4; ++f) sL[split][f][r] = l_[f];
    }
    __syncthreads();

    // 512 threads: each handles (qq, dv0) and (qq, dv0+8)
    const int qq  = threadIdx.x & 63;
    const int f   = qq >> 4;
    const int rr  = qq & 15;
    const int dv0 = threadIdx.x >> 6;           // 0..7
    const int b = bh >> 2, h = bh & 3;

    float den = 0.f;
    #pragma unroll
    for (int s = 0; s < KSPLIT; ++s) den += sL[s][f][rr];
    const float rd = 1.0f / den;

    #pragma unroll
    for (int dd = 0; dd < 2; ++dd) {
        const int dv = dv0 + dd * 8;
        float num = 0.f;
        #pragma unroll
        for (int s = 0; s < KSPLIT; ++s) num += sO[s][f][dv][rr];
        O2T[((size_t)b * CC + h * DKK + dv) * NN + qg * 64 + qq] = num * rd;
    }
}

// ---------------------------------------------------------------------------
// Stage 3: y[b,c,n] = sum_{h,v} o[b,h,n,v] * wo[h,c,v] / 8.
// 4 c-outputs per thread; wo reads are block-uniform (scalar cache).
// ---------------------------------------------------------------------------
__global__ __launch_bounds__(256) void out_kernel(
    const float* __restrict__ O2T, const float* __restrict__ wo,
    float* __restrict__ y)
{
    const int idx = blockIdx.x * 256 + threadIdx.x;   // (b*16 + cg)*NN + n
    const int n   = idx & (NN - 1);
    const int bcg = idx >> 12;
    const int cg  = bcg & 15;                         // c-group of 4
    const int b   = bcg >> 4;

    const float* ob = O2T + (size_t)b * CC * NN + n;
    float acc[4] = {0.f, 0.f, 0.f, 0.f};
    #pragma unroll
    for (int h = 0; h < NHEADS; ++h)
        #pragma unroll
        for (int v = 0; v < DKK; ++v) {
            const float o = ob[(size_t)(h * DKK + v) * NN];
            #pragma unroll
            for (int c2 = 0; c2 < 4; ++c2)
                acc[c2] += o * wo[((size_t)h * CC + cg * 4 + c2) * DKK + v];
        }
    #pragma unroll
    for (int c2 = 0; c2 < 4; ++c2)
        y[((size_t)b * CC + cg * 4 + c2) * NN + n] = acc[c2] * 0.125f;
}

// ---------------------------------------------------------------------------
extern "C" void kernel_launch(void* const* d_in, const int* in_sizes, int n_in,
                              void* d_out, int out_size, void* d_ws, size_t ws_size,
                              hipStream_t stream)
{
    const float* x  = (const float*)d_in[0];
    const float* wq = (const float*)d_in[1];
    const float* wk = (const float*)d_in[2];
    const float* wv = (const float*)d_in[3];
    const float* wo = (const float*)d_in[4];
    float* y = (float*)d_out;

    const size_t QKE = (size_t)NBH * NN * 16;           // QP/KP: 512K shorts
    const size_t VE  = (size_t)NBH * DKK * 128 * 32;    // VP: 512K shorts (hi-only)
    unsigned short* QP = (unsigned short*)d_ws;
    unsigned short* KP = QP + QKE;
    unsigned short* VP = KP + QKE;
    float* O2T = (float*)(VP + VE);

    proj_kernel<<<NBH * 64, 256, 0, stream>>>(x, wq, wk, wv, QP, KP, VP);
    attn_kernel<<<NBH * 64, 512, 0, stream>>>(QP, KP, VP, O2T);
    out_kernel<<<(BB * 16 * NN) / 256, 256, 0, stream>>>(O2T, wo, y);
}